// Round 4
// baseline (516.582 us; speedup 1.0000x reference)
//
#include <hip/hip_runtime.h>

#define NT 64
#define NBMAX 4096   // max 64-node buckets supported by the LDS-hist path

// ---------------------------------------------------------------------------
// Kernel 1: five 64x64 GEMMs over all nodes.
//   m in [0,3] -> y[m] = x @ weight[m]   (to workspace)
//   m == 4     -> out  = x @ root_w + b  (initializes out)
// ---------------------------------------------------------------------------
__global__ __launch_bounds__(256) void gemm5_kernel(
    const float* __restrict__ x, const float* __restrict__ weight,
    const float* __restrict__ root_w, const float* __restrict__ root_b,
    float* __restrict__ out, float* __restrict__ y, int n_nodes, int m_off)
{
    __shared__ float xs[NT][65];
    __shared__ float ws[64][65];

    const int tid   = threadIdx.x;
    const int m     = blockIdx.y + m_off;
    const int node0 = blockIdx.x * NT;
    const float* __restrict__ W = (m < 4) ? (weight + m * 4096) : root_w;

    #pragma unroll
    for (int i = 0; i < 4; ++i) {
        int v  = tid + i * 256;
        int r  = v >> 4;
        int cq = v & 15;
        float4 w4 = reinterpret_cast<const float4*>(W)[v];
        ws[r][cq * 4 + 0] = w4.x; ws[r][cq * 4 + 1] = w4.y;
        ws[r][cq * 4 + 2] = w4.z; ws[r][cq * 4 + 3] = w4.w;
        int node = node0 + r;
        float4 x4 = (node < n_nodes)
                        ? reinterpret_cast<const float4*>(x)[node * 16 + cq]
                        : make_float4(0.f, 0.f, 0.f, 0.f);
        xs[r][cq * 4 + 0] = x4.x; xs[r][cq * 4 + 1] = x4.y;
        xs[r][cq * 4 + 2] = x4.z; xs[r][cq * 4 + 3] = x4.w;
    }
    __syncthreads();

    const int tc = (tid & 15) * 4;
    const int tr = (tid >> 4) * 4;

    float acc[4][4];
    #pragma unroll
    for (int i = 0; i < 4; ++i)
        #pragma unroll
        for (int j = 0; j < 4; ++j) acc[i][j] = 0.f;

    #pragma unroll 4
    for (int k = 0; k < 64; ++k) {
        float xv[4], wv[4];
        #pragma unroll
        for (int i = 0; i < 4; ++i) xv[i] = xs[tr + i][k];
        #pragma unroll
        for (int j = 0; j < 4; ++j) wv[j] = ws[k][tc + j];
        #pragma unroll
        for (int i = 0; i < 4; ++i)
            #pragma unroll
            for (int j = 0; j < 4; ++j) acc[i][j] += xv[i] * wv[j];
    }

    float bias[4] = {0.f, 0.f, 0.f, 0.f};
    if (m == 4) {
        #pragma unroll
        for (int j = 0; j < 4; ++j) bias[j] = root_b[tc + j];
    }
    float* __restrict__ dst = (m < 4) ? (y + (size_t)m * n_nodes * 64) : out;
    #pragma unroll
    for (int i = 0; i < 4; ++i) {
        int node = node0 + tr + i;
        if (node < n_nodes) {
            float4 o = make_float4(acc[i][0] + bias[0], acc[i][1] + bias[1],
                                   acc[i][2] + bias[2], acc[i][3] + bias[3]);
            reinterpret_cast<float4*>(dst)[node * 16 + (tc >> 2)] = o;
        }
    }
}

// ------------------- bucketed (64-node) CSR build pipeline -----------------
// Kernel A: per-bucket histogram via LDS, few global atomics.
__global__ __launch_bounds__(256) void hist_kernel(
    const int* __restrict__ ei, int* __restrict__ gcount, int n_edges, int nb)
{
    __shared__ int lh[NBMAX];
    for (int i = threadIdx.x; i < nb; i += 256) lh[i] = 0;
    __syncthreads();
    const int stride = gridDim.x * 256;
    for (int e = blockIdx.x * 256 + threadIdx.x; e < n_edges; e += stride)
        atomicAdd(&lh[ei[n_edges + e] >> 6], 1);
    __syncthreads();
    for (int i = threadIdx.x; i < nb; i += 256)
        if (lh[i]) atomicAdd(&gcount[i], lh[i]);
}

// Kernel B: single-block exclusive scan over nb (<= 4096) buckets.
__global__ __launch_bounds__(1024) void scan_small_kernel(
    const int* __restrict__ gcount, int* __restrict__ offsets,
    int* __restrict__ cursor, int nb)
{
    __shared__ int part[1024];
    const int tid = threadIdx.x;
    int v[4]; int s = 0;
    #pragma unroll
    for (int i = 0; i < 4; ++i) {
        int idx = tid * 4 + i;
        v[i] = (idx < nb) ? gcount[idx] : 0;
        s += v[i];
    }
    part[tid] = s;
    __syncthreads();
    for (int d = 1; d < 1024; d <<= 1) {
        int t = (tid >= d) ? part[tid - d] : 0;
        __syncthreads();
        part[tid] += t;
        __syncthreads();
    }
    int run = (tid == 0) ? 0 : part[tid - 1];
    #pragma unroll
    for (int i = 0; i < 4; ++i) {
        int idx = tid * 4 + i;
        if (idx < nb) { offsets[idx] = run; cursor[idx] = run; run += v[i]; }
    }
    if (tid == 1023) offsets[nb] = part[1023];
}

// Kernel C: bin edges into bucket runs. Per-block LDS hist -> one cursor
// atomic per (block,bucket) reserves a contiguous run -> ranked writes.
// payload = src | (dst&63)<<ssh | type<<tsh  (one 32-bit word per edge)
__global__ __launch_bounds__(256) void fillb_kernel(
    const int* __restrict__ ei, const int* __restrict__ et,
    int* __restrict__ cursor, unsigned* __restrict__ payload,
    int n_edges, int nb, int ssh, int tsh)
{
    __shared__ int lh[NBMAX];
    __shared__ int lbase[NBMAX];
    const int chunk = (n_edges + gridDim.x - 1) / gridDim.x;
    const int lo = blockIdx.x * chunk;
    const int hi = min(lo + chunk, n_edges);
    for (int i = threadIdx.x; i < nb; i += 256) lh[i] = 0;
    __syncthreads();
    for (int e = lo + threadIdx.x; e < hi; e += 256)
        atomicAdd(&lh[ei[n_edges + e] >> 6], 1);
    __syncthreads();
    for (int i = threadIdx.x; i < nb; i += 256) {
        int c = lh[i];
        lbase[i] = c ? atomicAdd(&cursor[i], c) : 0;
        lh[i] = 0;
    }
    __syncthreads();
    for (int e = lo + threadIdx.x; e < hi; e += 256) {
        int src = ei[e];
        int d   = ei[n_edges + e];
        int t   = et[e];
        int b   = d >> 6;
        int r   = atomicAdd(&lh[b], 1);
        payload[lbase[b] + r] = (unsigned)src | ((unsigned)(d & 63) << ssh)
                              | ((unsigned)t << tsh);
    }
}

// Kernel D: one block per 64-node bucket. Coalesced payload reads, y-row
// gather (256B contiguous, L3-resident), LDS f32 atomic accumulate, then
// coalesced float4 RMW of out.
__global__ __launch_bounds__(256) void gatherb_kernel(
    const int* __restrict__ offsets, const unsigned* __restrict__ payload,
    const float* __restrict__ y, float* __restrict__ out,
    int n_nodes, int ssh, int tsh)
{
    __shared__ float acc[64 * 65];
    const int tid = threadIdx.x;
    const int b   = blockIdx.x;
    for (int i = tid; i < 64 * 65; i += 256) acc[i] = 0.f;
    __syncthreads();

    const int beg = offsets[b];
    const int end = offsets[b + 1];
    const int cq  = tid & 15;
    const unsigned smask = (1u << ssh) - 1;

    for (int p = beg + (tid >> 4); p < end; p += 16) {
        unsigned pl = payload[p];
        int src  = (int)(pl & smask);
        int ldst = (int)((pl >> ssh) & 63);
        int t    = (int)(pl >> tsh);
        float4 v = reinterpret_cast<const float4*>(y)[((long)t * n_nodes + src) * 16 + cq];
        float* a = &acc[ldst * 65 + cq * 4];
        atomicAdd(a + 0, v.x);
        atomicAdd(a + 1, v.y);
        atomicAdd(a + 2, v.z);
        atomicAdd(a + 3, v.w);
    }
    __syncthreads();

    #pragma unroll
    for (int i = 0; i < 4; ++i) {
        int f4 = tid + i * 256;        // 0..1023 float4 slots
        int r  = f4 >> 4;
        int q  = f4 & 15;
        int node = b * 64 + r;
        if (node < n_nodes) {
            float4* o  = reinterpret_cast<float4*>(out) + (long)node * 16 + q;
            float4 cur = *o;
            cur.x += acc[r * 65 + q * 4 + 0];
            cur.y += acc[r * 65 + q * 4 + 1];
            cur.z += acc[r * 65 + q * 4 + 2];
            cur.w += acc[r * 65 + q * 4 + 3];
            *o = cur;
        }
    }
}

// --------------------- fallback: atomic scatter (round-1) ------------------
__global__ __launch_bounds__(256) void scatter_kernel(
    const int* __restrict__ ei, const int* __restrict__ et,
    const float* __restrict__ y, float* __restrict__ out,
    int n_edges, int n_nodes)
{
    long idx = (long)blockIdx.x * blockDim.x + threadIdx.x;
    if (idx >= (long)n_edges * 16) return;
    int e  = (int)(idx >> 4);
    int cq = (int)(idx & 15);
    int src  = ei[e];
    int dstn = ei[n_edges + e];
    int t    = et[e];
    float4 v = reinterpret_cast<const float4*>(y)[((long)t * n_nodes + src) * 16 + cq];
    float* o = out + (long)dstn * 64 + cq * 4;
    atomicAdd(o + 0, v.x);
    atomicAdd(o + 1, v.y);
    atomicAdd(o + 2, v.z);
    atomicAdd(o + 3, v.w);
}

__global__ __launch_bounds__(256) void edge_direct_kernel(
    const float* __restrict__ x, const int* __restrict__ ei,
    const int* __restrict__ et, const float* __restrict__ weight,
    float* __restrict__ out, int n_edges)
{
    int gwave  = (int)((blockIdx.x * (long)blockDim.x + threadIdx.x) >> 6);
    int lane   = threadIdx.x & 63;
    int nwaves = (int)(((long)gridDim.x * blockDim.x) >> 6);
    for (int e = gwave; e < n_edges; e += nwaves) {
        int src  = ei[e];
        int dstn = ei[n_edges + e];
        int t    = et[e];
        float xv = x[src * 64 + lane];
        const float* __restrict__ W = weight + t * 4096;
        float acc = 0.f;
        #pragma unroll 8
        for (int k = 0; k < 64; ++k) {
            float xk = __shfl(xv, k);
            acc += xk * W[k * 64 + lane];
        }
        atomicAdd(&out[(long)dstn * 64 + lane], acc);
    }
}

extern "C" void kernel_launch(void* const* d_in, const int* in_sizes, int n_in,
                              void* d_out, int out_size, void* d_ws, size_t ws_size,
                              hipStream_t stream) {
    const float* x      = (const float*)d_in[0];
    const int*   ei     = (const int*)d_in[1];   // [2, E] int32
    const int*   et     = (const int*)d_in[2];   // [E]
    const float* weight = (const float*)d_in[3]; // [4, 64, 64]
    const float* root_w = (const float*)d_in[4]; // [64, 64]
    const float* root_b = (const float*)d_in[5]; // [64]
    float* out = (float*)d_out;

    const int n_nodes = in_sizes[0] / 64;
    const int n_edges = in_sizes[2];
    const int nb      = (n_nodes + 63) >> 6;

    int ssh = 1;
    while ((1 << ssh) < n_nodes) ++ssh;   // bits for src
    const int tsh = ssh + 6;              // 6 bits for local dst

    const size_t y_bytes  = (size_t)4 * n_nodes * 64 * sizeof(float);
    const size_t b_bytes  = y_bytes + ((size_t)3 * nb + 1 + n_edges) * 4;

    const int node_blocks = (n_nodes + NT - 1) / NT;

    if (nb <= NBMAX && tsh + 2 <= 32 && ws_size >= b_bytes) {
        float*    y       = (float*)d_ws;
        int*      gcount  = (int*)((char*)d_ws + y_bytes);
        int*      offsets = gcount + nb;              // nb+1
        int*      cursor  = offsets + nb + 1;
        unsigned* payload = (unsigned*)(cursor + nb);

        hipMemsetAsync(gcount, 0, (size_t)nb * 4, stream);
        hist_kernel<<<256, 256, 0, stream>>>(ei, gcount, n_edges, nb);
        scan_small_kernel<<<1, 1024, 0, stream>>>(gcount, offsets, cursor, nb);
        fillb_kernel<<<256, 256, 0, stream>>>(ei, et, cursor, payload,
                                              n_edges, nb, ssh, tsh);
        dim3 grid(node_blocks, 5);
        gemm5_kernel<<<grid, 256, 0, stream>>>(x, weight, root_w, root_b,
                                               out, y, n_nodes, 0);
        gatherb_kernel<<<nb, 256, 0, stream>>>(offsets, payload, y, out,
                                               n_nodes, ssh, tsh);
    } else if (ws_size >= y_bytes) {
        float* y = (float*)d_ws;
        dim3 grid(node_blocks, 5);
        gemm5_kernel<<<grid, 256, 0, stream>>>(x, weight, root_w, root_b,
                                               out, y, n_nodes, 0);
        long total  = (long)n_edges * 16;
        int  blocks = (int)((total + 255) / 256);
        scatter_kernel<<<blocks, 256, 0, stream>>>(ei, et, y, out, n_edges, n_nodes);
    } else {
        dim3 grid(node_blocks, 1);
        gemm5_kernel<<<grid, 256, 0, stream>>>(x, weight, root_w, root_b,
                                               out, nullptr, n_nodes, 4);
        edge_direct_kernel<<<4096, 256, 0, stream>>>(x, ei, et, weight, out, n_edges);
    }
}

// Round 5
// 137.331 us; speedup vs baseline: 3.7616x; 3.7616x over previous
//
#include <hip/hip_runtime.h>

#define NT 64
#define NBMAX 4096   // max 64-node buckets supported by the LDS-hist path
#define CAP  4096    // max edges per bucket handled by in-LDS sort

// ---------------------------------------------------------------------------
// Kernel 1: five 64x64 GEMMs over all nodes.
//   m in [0,3] -> y[m] = x @ weight[m]   (to workspace)
//   m == 4     -> out  = x @ root_w + b  (initializes out)
// ---------------------------------------------------------------------------
__global__ __launch_bounds__(256) void gemm5_kernel(
    const float* __restrict__ x, const float* __restrict__ weight,
    const float* __restrict__ root_w, const float* __restrict__ root_b,
    float* __restrict__ out, float* __restrict__ y, int n_nodes, int m_off)
{
    __shared__ float xs[NT][65];
    __shared__ float ws[64][65];

    const int tid   = threadIdx.x;
    const int m     = blockIdx.y + m_off;
    const int node0 = blockIdx.x * NT;
    const float* __restrict__ W = (m < 4) ? (weight + m * 4096) : root_w;

    #pragma unroll
    for (int i = 0; i < 4; ++i) {
        int v  = tid + i * 256;
        int r  = v >> 4;
        int cq = v & 15;
        float4 w4 = reinterpret_cast<const float4*>(W)[v];
        ws[r][cq * 4 + 0] = w4.x; ws[r][cq * 4 + 1] = w4.y;
        ws[r][cq * 4 + 2] = w4.z; ws[r][cq * 4 + 3] = w4.w;
        int node = node0 + r;
        float4 x4 = (node < n_nodes)
                        ? reinterpret_cast<const float4*>(x)[node * 16 + cq]
                        : make_float4(0.f, 0.f, 0.f, 0.f);
        xs[r][cq * 4 + 0] = x4.x; xs[r][cq * 4 + 1] = x4.y;
        xs[r][cq * 4 + 2] = x4.z; xs[r][cq * 4 + 3] = x4.w;
    }
    __syncthreads();

    const int tc = (tid & 15) * 4;
    const int tr = (tid >> 4) * 4;

    float acc[4][4];
    #pragma unroll
    for (int i = 0; i < 4; ++i)
        #pragma unroll
        for (int j = 0; j < 4; ++j) acc[i][j] = 0.f;

    #pragma unroll 4
    for (int k = 0; k < 64; ++k) {
        float xv[4], wv[4];
        #pragma unroll
        for (int i = 0; i < 4; ++i) xv[i] = xs[tr + i][k];
        #pragma unroll
        for (int j = 0; j < 4; ++j) wv[j] = ws[k][tc + j];
        #pragma unroll
        for (int i = 0; i < 4; ++i)
            #pragma unroll
            for (int j = 0; j < 4; ++j) acc[i][j] += xv[i] * wv[j];
    }

    float bias[4] = {0.f, 0.f, 0.f, 0.f};
    if (m == 4) {
        #pragma unroll
        for (int j = 0; j < 4; ++j) bias[j] = root_b[tc + j];
    }
    float* __restrict__ dst = (m < 4) ? (y + (size_t)m * n_nodes * 64) : out;
    #pragma unroll
    for (int i = 0; i < 4; ++i) {
        int node = node0 + tr + i;
        if (node < n_nodes) {
            float4 o = make_float4(acc[i][0] + bias[0], acc[i][1] + bias[1],
                                   acc[i][2] + bias[2], acc[i][3] + bias[3]);
            reinterpret_cast<float4*>(dst)[node * 16 + (tc >> 2)] = o;
        }
    }
}

// ------------------- bucketed (64-node) CSR build pipeline -----------------
__global__ __launch_bounds__(256) void hist_kernel(
    const int* __restrict__ ei, int* __restrict__ gcount, int n_edges, int nb)
{
    __shared__ int lh[NBMAX];
    for (int i = threadIdx.x; i < nb; i += 256) lh[i] = 0;
    __syncthreads();
    const int stride = gridDim.x * 256;
    for (int e = blockIdx.x * 256 + threadIdx.x; e < n_edges; e += stride)
        atomicAdd(&lh[ei[n_edges + e] >> 6], 1);
    __syncthreads();
    for (int i = threadIdx.x; i < nb; i += 256)
        if (lh[i]) atomicAdd(&gcount[i], lh[i]);
}

__global__ __launch_bounds__(1024) void scan_small_kernel(
    const int* __restrict__ gcount, int* __restrict__ offsets,
    int* __restrict__ cursor, int nb)
{
    __shared__ int part[1024];
    const int tid = threadIdx.x;
    int v[4]; int s = 0;
    #pragma unroll
    for (int i = 0; i < 4; ++i) {
        int idx = tid * 4 + i;
        v[i] = (idx < nb) ? gcount[idx] : 0;
        s += v[i];
    }
    part[tid] = s;
    __syncthreads();
    for (int d = 1; d < 1024; d <<= 1) {
        int t = (tid >= d) ? part[tid - d] : 0;
        __syncthreads();
        part[tid] += t;
        __syncthreads();
    }
    int run = (tid == 0) ? 0 : part[tid - 1];
    #pragma unroll
    for (int i = 0; i < 4; ++i) {
        int idx = tid * 4 + i;
        if (idx < nb) { offsets[idx] = run; cursor[idx] = run; run += v[i]; }
    }
    if (tid == 1023) offsets[nb] = part[1023];
}

// payload = src | (dst&63)<<ssh | type<<tsh
__global__ __launch_bounds__(256) void fillb_kernel(
    const int* __restrict__ ei, const int* __restrict__ et,
    int* __restrict__ cursor, unsigned* __restrict__ payload,
    int n_edges, int nb, int ssh, int tsh)
{
    __shared__ int lh[NBMAX];
    __shared__ int lbase[NBMAX];
    const int chunk = (n_edges + gridDim.x - 1) / gridDim.x;
    const int lo = blockIdx.x * chunk;
    const int hi = min(lo + chunk, n_edges);
    for (int i = threadIdx.x; i < nb; i += 256) lh[i] = 0;
    __syncthreads();
    for (int e = lo + threadIdx.x; e < hi; e += 256)
        atomicAdd(&lh[ei[n_edges + e] >> 6], 1);
    __syncthreads();
    for (int i = threadIdx.x; i < nb; i += 256) {
        int c = lh[i];
        lbase[i] = c ? atomicAdd(&cursor[i], c) : 0;
        lh[i] = 0;
    }
    __syncthreads();
    for (int e = lo + threadIdx.x; e < hi; e += 256) {
        int src = ei[e];
        int d   = ei[n_edges + e];
        int t   = et[e];
        int b   = d >> 6;
        int r   = atomicAdd(&lh[b], 1);
        payload[lbase[b] + r] = (unsigned)src | ((unsigned)(d & 63) << ssh)
                              | ((unsigned)t << tsh);
    }
}

// ---------------------------------------------------------------------------
// Gather v2: one 1024-thread block per bucket.
//   Phase 1: in-LDS counting sort of the bucket's payload by local dst.
//   Phase 2: 64 groups x 16 threads; group g owns node b*64+g, loops over its
//            sorted entries with a REGISTER float4 accumulator (no atomics).
// ---------------------------------------------------------------------------
__global__ __launch_bounds__(1024) void gatherb2_kernel(
    const int* __restrict__ offsets, const unsigned* __restrict__ payload,
    const float* __restrict__ y, float* __restrict__ out,
    int n_nodes, int ssh, int tsh)
{
    __shared__ unsigned raw[CAP];
    __shared__ unsigned srt[CAP];
    __shared__ int hist[64];
    __shared__ int hoff[65];

    const int tid = threadIdx.x;
    const int b   = blockIdx.x;
    const int beg = offsets[b];
    const int end = offsets[b + 1];
    const int cnt  = end - beg;
    const int n_in = min(cnt, CAP);

    if (tid < 64) hist[tid] = 0;
    __syncthreads();
    for (int i = tid; i < n_in; i += 1024) {
        unsigned pl = payload[beg + i];
        raw[i] = pl;
        atomicAdd(&hist[(pl >> ssh) & 63], 1);
    }
    __syncthreads();
    if (tid < 64) {                       // wave-parallel exclusive scan, 64 bins
        int v = hist[tid];
        int s = v;
        #pragma unroll
        for (int d = 1; d < 64; d <<= 1) {
            int u = __shfl_up(s, d, 64);
            if (tid >= d) s += u;
        }
        hoff[tid] = s - v;
        if (tid == 63) hoff[64] = s;
        hist[tid] = 0;
    }
    __syncthreads();
    for (int i = tid; i < n_in; i += 1024) {
        unsigned pl = raw[i];
        int l = (pl >> ssh) & 63;
        int r = atomicAdd(&hist[l], 1);
        srt[hoff[l] + r] = pl;
    }
    __syncthreads();

    const int g    = tid >> 4;            // node row within bucket
    const int cq   = tid & 15;            // channel quad
    const int node = b * 64 + g;
    const unsigned smask = (1u << ssh) - 1;

    float4 acc = make_float4(0.f, 0.f, 0.f, 0.f);
    const int s0 = hoff[g];
    const int s1 = hoff[g + 1];
    for (int p = s0; p < s1; ++p) {
        unsigned pl = srt[p];
        int src = (int)(pl & smask);
        int t   = (int)(pl >> tsh);
        float4 v = reinterpret_cast<const float4*>(y)[((long)t * n_nodes + src) * 16 + cq];
        acc.x += v.x; acc.y += v.y; acc.z += v.z; acc.w += v.w;
    }
    if (node < n_nodes) {
        float4* o  = reinterpret_cast<float4*>(out) + (long)node * 16 + cq;
        float4 cur = *o;
        cur.x += acc.x; cur.y += acc.y; cur.z += acc.z; cur.w += acc.w;
        *o = cur;
    }

    // Overflow entries (cnt > CAP): never for this input; correctness fallback.
    for (int i = CAP + tid; i < cnt; i += 1024) {
        unsigned pl = payload[beg + i];
        int src = (int)(pl & smask);
        int l   = (int)((pl >> ssh) & 63);
        int t   = (int)(pl >> tsh);
        for (int c = 0; c < 64; ++c)
            atomicAdd(&out[(long)(b * 64 + l) * 64 + c],
                      y[((long)t * n_nodes + src) * 64 + c]);
    }
}

// --------------------- fallback: atomic scatter (round-1) ------------------
__global__ __launch_bounds__(256) void scatter_kernel(
    const int* __restrict__ ei, const int* __restrict__ et,
    const float* __restrict__ y, float* __restrict__ out,
    int n_edges, int n_nodes)
{
    long idx = (long)blockIdx.x * blockDim.x + threadIdx.x;
    if (idx >= (long)n_edges * 16) return;
    int e  = (int)(idx >> 4);
    int cq = (int)(idx & 15);
    int src  = ei[e];
    int dstn = ei[n_edges + e];
    int t    = et[e];
    float4 v = reinterpret_cast<const float4*>(y)[((long)t * n_nodes + src) * 16 + cq];
    float* o = out + (long)dstn * 64 + cq * 4;
    atomicAdd(o + 0, v.x);
    atomicAdd(o + 1, v.y);
    atomicAdd(o + 2, v.z);
    atomicAdd(o + 3, v.w);
}

__global__ __launch_bounds__(256) void edge_direct_kernel(
    const float* __restrict__ x, const int* __restrict__ ei,
    const int* __restrict__ et, const float* __restrict__ weight,
    float* __restrict__ out, int n_edges)
{
    int gwave  = (int)((blockIdx.x * (long)blockDim.x + threadIdx.x) >> 6);
    int lane   = threadIdx.x & 63;
    int nwaves = (int)(((long)gridDim.x * blockDim.x) >> 6);
    for (int e = gwave; e < n_edges; e += nwaves) {
        int src  = ei[e];
        int dstn = ei[n_edges + e];
        int t    = et[e];
        float xv = x[src * 64 + lane];
        const float* __restrict__ W = weight + t * 4096;
        float acc = 0.f;
        #pragma unroll 8
        for (int k = 0; k < 64; ++k) {
            float xk = __shfl(xv, k);
            acc += xk * W[k * 64 + lane];
        }
        atomicAdd(&out[(long)dstn * 64 + lane], acc);
    }
}

extern "C" void kernel_launch(void* const* d_in, const int* in_sizes, int n_in,
                              void* d_out, int out_size, void* d_ws, size_t ws_size,
                              hipStream_t stream) {
    const float* x      = (const float*)d_in[0];
    const int*   ei     = (const int*)d_in[1];   // [2, E] int32
    const int*   et     = (const int*)d_in[2];   // [E]
    const float* weight = (const float*)d_in[3]; // [4, 64, 64]
    const float* root_w = (const float*)d_in[4]; // [64, 64]
    const float* root_b = (const float*)d_in[5]; // [64]
    float* out = (float*)d_out;

    const int n_nodes = in_sizes[0] / 64;
    const int n_edges = in_sizes[2];
    const int nb      = (n_nodes + 63) >> 6;

    int ssh = 1;
    while ((1 << ssh) < n_nodes) ++ssh;   // bits for src
    const int tsh = ssh + 6;              // 6 bits for local dst

    const size_t y_bytes  = (size_t)4 * n_nodes * 64 * sizeof(float);
    const size_t b_bytes  = y_bytes + ((size_t)3 * nb + 1 + n_edges) * 4;

    const int node_blocks = (n_nodes + NT - 1) / NT;

    if (nb <= NBMAX && tsh + 2 <= 32 && ws_size >= b_bytes) {
        float*    y       = (float*)d_ws;
        int*      gcount  = (int*)((char*)d_ws + y_bytes);
        int*      offsets = gcount + nb;              // nb+1
        int*      cursor  = offsets + nb + 1;
        unsigned* payload = (unsigned*)(cursor + nb);

        hipMemsetAsync(gcount, 0, (size_t)nb * 4, stream);
        hist_kernel<<<256, 256, 0, stream>>>(ei, gcount, n_edges, nb);
        scan_small_kernel<<<1, 1024, 0, stream>>>(gcount, offsets, cursor, nb);
        fillb_kernel<<<256, 256, 0, stream>>>(ei, et, cursor, payload,
                                              n_edges, nb, ssh, tsh);
        dim3 grid(node_blocks, 5);
        gemm5_kernel<<<grid, 256, 0, stream>>>(x, weight, root_w, root_b,
                                               out, y, n_nodes, 0);
        gatherb2_kernel<<<nb, 1024, 0, stream>>>(offsets, payload, y, out,
                                                 n_nodes, ssh, tsh);
    } else if (ws_size >= y_bytes) {
        float* y = (float*)d_ws;
        dim3 grid(node_blocks, 5);
        gemm5_kernel<<<grid, 256, 0, stream>>>(x, weight, root_w, root_b,
                                               out, y, n_nodes, 0);
        long total  = (long)n_edges * 16;
        int  blocks = (int)((total + 255) / 256);
        scatter_kernel<<<blocks, 256, 0, stream>>>(ei, et, y, out, n_edges, n_nodes);
    } else {
        dim3 grid(node_blocks, 1);
        gemm5_kernel<<<grid, 256, 0, stream>>>(x, weight, root_w, root_b,
                                               out, nullptr, n_nodes, 4);
        edge_direct_kernel<<<4096, 256, 0, stream>>>(x, ei, et, weight, out, n_edges);
    }
}

// Round 6
// 126.294 us; speedup vs baseline: 4.0903x; 1.0874x over previous
//
#include <hip/hip_runtime.h>

#define NT 64
#define NBMAX 4096   // max 64-node buckets supported by the LDS-hist path
#define CAP  4096    // max edges per bucket handled by in-LDS sort

__device__ __forceinline__ unsigned short f2bf(float f) {
    unsigned u = __builtin_bit_cast(unsigned, f);
    unsigned r = (u + 0x7fffu + ((u >> 16) & 1u)) >> 16;   // round-nearest-even
    return (unsigned short)r;
}
__device__ __forceinline__ float bf2f(unsigned short h) {
    return __builtin_bit_cast(float, (unsigned)h << 16);
}

// ---------------------------------------------------------------------------
// Fused GEMM: one pass over x computes all 5 products.
//   m in [0,3] -> y[m] = x @ weight[m]   (bf16, to workspace)
//   m == 4     -> out  = x @ root_w + b  (f32, initializes out)
// 256-node tile, x staged TRANSPOSED in LDS as bf16 -> vector A reads.
// Thread tile: 8 nodes x 8 cols.
// ---------------------------------------------------------------------------
__global__ __launch_bounds__(256) void gemm_fused_kernel(
    const float* __restrict__ x, const float* __restrict__ weight,
    const float* __restrict__ root_w, const float* __restrict__ root_b,
    float* __restrict__ out, unsigned short* __restrict__ y, int n_nodes)
{
    __shared__ unsigned short xsT[64][264];  // [k][node], bf16, row=528B (16B-aligned)
    __shared__ float ws[64][72];             // [k][col], row=288B (16B-aligned)

    const int tid   = threadIdx.x;
    const int node0 = blockIdx.x * 256;

    // Stage x tile transposed (coalesced float4 global reads, b16 LDS scatter).
    #pragma unroll
    for (int i = 0; i < 16; ++i) {
        int v    = tid + i * 256;      // 0..4095 : 256 nodes x 16 quads
        int r    = v >> 4;
        int cq   = v & 15;
        int node = node0 + r;
        float4 x4 = (node < n_nodes)
                        ? reinterpret_cast<const float4*>(x)[(size_t)node * 16 + cq]
                        : make_float4(0.f, 0.f, 0.f, 0.f);
        xsT[cq * 4 + 0][r] = f2bf(x4.x);
        xsT[cq * 4 + 1][r] = f2bf(x4.y);
        xsT[cq * 4 + 2][r] = f2bf(x4.z);
        xsT[cq * 4 + 3][r] = f2bf(x4.w);
    }

    const int ng = tid >> 3;    // node group: nodes ng*8 .. ng*8+7
    const int cg = tid & 7;     // col group : cols  cg*8 .. cg*8+7

    float bias[8];
    #pragma unroll
    for (int j = 0; j < 8; ++j) bias[j] = root_b[cg * 8 + j];

    for (int m = 0; m < 5; ++m) {
        const float* __restrict__ W = (m < 4) ? (weight + m * 4096) : root_w;
        __syncthreads();               // prev readers of ws done / xsT visible
        #pragma unroll
        for (int i = 0; i < 4; ++i) {
            int v  = tid + i * 256;    // 0..1023
            int r  = v >> 4;
            int cq = v & 15;
            float4 w4 = reinterpret_cast<const float4*>(W)[v];
            ws[r][cq * 4 + 0] = w4.x; ws[r][cq * 4 + 1] = w4.y;
            ws[r][cq * 4 + 2] = w4.z; ws[r][cq * 4 + 3] = w4.w;
        }
        __syncthreads();

        float acc[8][8];
        #pragma unroll
        for (int i = 0; i < 8; ++i)
            #pragma unroll
            for (int j = 0; j < 8; ++j) acc[i][j] = 0.f;

        #pragma unroll 2
        for (int k = 0; k < 64; ++k) {
            uint4 xu = *reinterpret_cast<const uint4*>(&xsT[k][ng * 8]);
            float xv[8];
            xv[0] = __builtin_bit_cast(float, xu.x << 16);
            xv[1] = __builtin_bit_cast(float, xu.x & 0xffff0000u);
            xv[2] = __builtin_bit_cast(float, xu.y << 16);
            xv[3] = __builtin_bit_cast(float, xu.y & 0xffff0000u);
            xv[4] = __builtin_bit_cast(float, xu.z << 16);
            xv[5] = __builtin_bit_cast(float, xu.z & 0xffff0000u);
            xv[6] = __builtin_bit_cast(float, xu.w << 16);
            xv[7] = __builtin_bit_cast(float, xu.w & 0xffff0000u);
            float4 wa = *reinterpret_cast<const float4*>(&ws[k][cg * 8]);
            float4 wb = *reinterpret_cast<const float4*>(&ws[k][cg * 8 + 4]);
            float wv[8] = {wa.x, wa.y, wa.z, wa.w, wb.x, wb.y, wb.z, wb.w};
            #pragma unroll
            for (int i = 0; i < 8; ++i)
                #pragma unroll
                for (int j = 0; j < 8; ++j) acc[i][j] += xv[i] * wv[j];
        }

        if (m < 4) {
            #pragma unroll
            for (int i = 0; i < 8; ++i) {
                int node = node0 + ng * 8 + i;
                if (node < n_nodes) {
                    uint4 o;
                    o.x = (unsigned)f2bf(acc[i][0]) | ((unsigned)f2bf(acc[i][1]) << 16);
                    o.y = (unsigned)f2bf(acc[i][2]) | ((unsigned)f2bf(acc[i][3]) << 16);
                    o.z = (unsigned)f2bf(acc[i][4]) | ((unsigned)f2bf(acc[i][5]) << 16);
                    o.w = (unsigned)f2bf(acc[i][6]) | ((unsigned)f2bf(acc[i][7]) << 16);
                    *reinterpret_cast<uint4*>(
                        &y[((size_t)m * n_nodes + node) * 64 + cg * 8]) = o;
                }
            }
        } else {
            #pragma unroll
            for (int i = 0; i < 8; ++i) {
                int node = node0 + ng * 8 + i;
                if (node < n_nodes) {
                    float4 oa = make_float4(acc[i][0] + bias[0], acc[i][1] + bias[1],
                                            acc[i][2] + bias[2], acc[i][3] + bias[3]);
                    float4 ob = make_float4(acc[i][4] + bias[4], acc[i][5] + bias[5],
                                            acc[i][6] + bias[6], acc[i][7] + bias[7]);
                    reinterpret_cast<float4*>(&out[(size_t)node * 64 + cg * 8])[0] = oa;
                    reinterpret_cast<float4*>(&out[(size_t)node * 64 + cg * 8])[1] = ob;
                }
            }
        }
    }
}

// ------------------- bucketed (64-node) CSR build pipeline -----------------
__global__ __launch_bounds__(256) void hist_kernel(
    const int* __restrict__ ei, int* __restrict__ gcount, int n_edges, int nb)
{
    __shared__ int lh[NBMAX];
    for (int i = threadIdx.x; i < nb; i += 256) lh[i] = 0;
    __syncthreads();
    const int stride = gridDim.x * 256;
    for (int e = blockIdx.x * 256 + threadIdx.x; e < n_edges; e += stride)
        atomicAdd(&lh[ei[n_edges + e] >> 6], 1);
    __syncthreads();
    for (int i = threadIdx.x; i < nb; i += 256)
        if (lh[i]) atomicAdd(&gcount[i], lh[i]);
}

__global__ __launch_bounds__(1024) void scan_small_kernel(
    const int* __restrict__ gcount, int* __restrict__ offsets,
    int* __restrict__ cursor, int nb)
{
    __shared__ int part[1024];
    const int tid = threadIdx.x;
    int v[4]; int s = 0;
    #pragma unroll
    for (int i = 0; i < 4; ++i) {
        int idx = tid * 4 + i;
        v[i] = (idx < nb) ? gcount[idx] : 0;
        s += v[i];
    }
    part[tid] = s;
    __syncthreads();
    for (int d = 1; d < 1024; d <<= 1) {
        int t = (tid >= d) ? part[tid - d] : 0;
        __syncthreads();
        part[tid] += t;
        __syncthreads();
    }
    int run = (tid == 0) ? 0 : part[tid - 1];
    #pragma unroll
    for (int i = 0; i < 4; ++i) {
        int idx = tid * 4 + i;
        if (idx < nb) { offsets[idx] = run; cursor[idx] = run; run += v[i]; }
    }
    if (tid == 1023) offsets[nb] = part[1023];
}

// payload = src | (dst&63)<<ssh | type<<tsh
__global__ __launch_bounds__(256) void fillb_kernel(
    const int* __restrict__ ei, const int* __restrict__ et,
    int* __restrict__ cursor, unsigned* __restrict__ payload,
    int n_edges, int nb, int ssh, int tsh)
{
    __shared__ int lh[NBMAX];
    __shared__ int lbase[NBMAX];
    const int chunk = (n_edges + gridDim.x - 1) / gridDim.x;
    const int lo = blockIdx.x * chunk;
    const int hi = min(lo + chunk, n_edges);
    for (int i = threadIdx.x; i < nb; i += 256) lh[i] = 0;
    __syncthreads();
    for (int e = lo + threadIdx.x; e < hi; e += 256)
        atomicAdd(&lh[ei[n_edges + e] >> 6], 1);
    __syncthreads();
    for (int i = threadIdx.x; i < nb; i += 256) {
        int c = lh[i];
        lbase[i] = c ? atomicAdd(&cursor[i], c) : 0;
        lh[i] = 0;
    }
    __syncthreads();
    for (int e = lo + threadIdx.x; e < hi; e += 256) {
        int src = ei[e];
        int d   = ei[n_edges + e];
        int t   = et[e];
        int b   = d >> 6;
        int r   = atomicAdd(&lh[b], 1);
        payload[lbase[b] + r] = (unsigned)src | ((unsigned)(d & 63) << ssh)
                              | ((unsigned)t << tsh);
    }
}

// ---------------------------------------------------------------------------
// Gather v2 (bf16 y): one 1024-thread block per bucket.
//   Phase 1: in-LDS counting sort of the bucket's payload by local dst.
//   Phase 2: 64 groups x 16 threads; group g owns node b*64+g, register acc.
// ---------------------------------------------------------------------------
__global__ __launch_bounds__(1024) void gatherb2_kernel(
    const int* __restrict__ offsets, const unsigned* __restrict__ payload,
    const unsigned short* __restrict__ y, float* __restrict__ out,
    int n_nodes, int ssh, int tsh)
{
    __shared__ unsigned raw[CAP];
    __shared__ unsigned srt[CAP];
    __shared__ int hist[64];
    __shared__ int hoff[65];

    const int tid = threadIdx.x;
    const int b   = blockIdx.x;
    const int beg = offsets[b];
    const int end = offsets[b + 1];
    const int cnt  = end - beg;
    const int n_in = min(cnt, CAP);

    if (tid < 64) hist[tid] = 0;
    __syncthreads();
    for (int i = tid; i < n_in; i += 1024) {
        unsigned pl = payload[beg + i];
        raw[i] = pl;
        atomicAdd(&hist[(pl >> ssh) & 63], 1);
    }
    __syncthreads();
    if (tid < 64) {                       // wave-parallel exclusive scan, 64 bins
        int v = hist[tid];
        int s = v;
        #pragma unroll
        for (int d = 1; d < 64; d <<= 1) {
            int u = __shfl_up(s, d, 64);
            if (tid >= d) s += u;
        }
        hoff[tid] = s - v;
        if (tid == 63) hoff[64] = s;
        hist[tid] = 0;
    }
    __syncthreads();
    for (int i = tid; i < n_in; i += 1024) {
        unsigned pl = raw[i];
        int l = (pl >> ssh) & 63;
        int r = atomicAdd(&hist[l], 1);
        srt[hoff[l] + r] = pl;
    }
    __syncthreads();

    const int g    = tid >> 4;            // node row within bucket
    const int cq   = tid & 15;            // channel quad
    const int node = b * 64 + g;
    const unsigned smask = (1u << ssh) - 1;

    float4 acc = make_float4(0.f, 0.f, 0.f, 0.f);
    const int s0 = hoff[g];
    const int s1 = hoff[g + 1];
    for (int p = s0; p < s1; ++p) {
        unsigned pl = srt[p];
        int src = (int)(pl & smask);
        int t   = (int)(pl >> tsh);
        ushort4 v = reinterpret_cast<const ushort4*>(y)[((long)t * n_nodes + src) * 16 + cq];
        acc.x += bf2f(v.x); acc.y += bf2f(v.y);
        acc.z += bf2f(v.z); acc.w += bf2f(v.w);
    }
    if (node < n_nodes) {
        float4* o  = reinterpret_cast<float4*>(out) + (long)node * 16 + cq;
        float4 cur = *o;
        cur.x += acc.x; cur.y += acc.y; cur.z += acc.z; cur.w += acc.w;
        *o = cur;
    }

    // Overflow entries (cnt > CAP): never for this input; correctness fallback.
    for (int i = CAP + tid; i < cnt; i += 1024) {
        unsigned pl = payload[beg + i];
        int src = (int)(pl & smask);
        int l   = (int)((pl >> ssh) & 63);
        int t   = (int)(pl >> tsh);
        for (int c = 0; c < 64; ++c)
            atomicAdd(&out[(long)(b * 64 + l) * 64 + c],
                      bf2f(y[((long)t * n_nodes + src) * 64 + c]));
    }
}

// --------------------- fallbacks (small workspace) -------------------------
__global__ __launch_bounds__(256) void scatter_kernel(
    const int* __restrict__ ei, const int* __restrict__ et,
    const unsigned short* __restrict__ y, float* __restrict__ out,
    int n_edges, int n_nodes)
{
    long idx = (long)blockIdx.x * blockDim.x + threadIdx.x;
    if (idx >= (long)n_edges * 16) return;
    int e  = (int)(idx >> 4);
    int cq = (int)(idx & 15);
    int src  = ei[e];
    int dstn = ei[n_edges + e];
    int t    = et[e];
    ushort4 v = reinterpret_cast<const ushort4*>(y)[((long)t * n_nodes + src) * 16 + cq];
    float* o = out + (long)dstn * 64 + cq * 4;
    atomicAdd(o + 0, bf2f(v.x));
    atomicAdd(o + 1, bf2f(v.y));
    atomicAdd(o + 2, bf2f(v.z));
    atomicAdd(o + 3, bf2f(v.w));
}

// root-only GEMM (no workspace at all)
__global__ __launch_bounds__(256) void gemm_root_kernel(
    const float* __restrict__ x, const float* __restrict__ root_w,
    const float* __restrict__ root_b, float* __restrict__ out, int n_nodes)
{
    __shared__ float xs[NT][65];
    __shared__ float ws[64][65];
    const int tid   = threadIdx.x;
    const int node0 = blockIdx.x * NT;
    #pragma unroll
    for (int i = 0; i < 4; ++i) {
        int v  = tid + i * 256;
        int r  = v >> 4;
        int cq = v & 15;
        float4 w4 = reinterpret_cast<const float4*>(root_w)[v];
        ws[r][cq * 4 + 0] = w4.x; ws[r][cq * 4 + 1] = w4.y;
        ws[r][cq * 4 + 2] = w4.z; ws[r][cq * 4 + 3] = w4.w;
        int node = node0 + r;
        float4 x4 = (node < n_nodes)
                        ? reinterpret_cast<const float4*>(x)[node * 16 + cq]
                        : make_float4(0.f, 0.f, 0.f, 0.f);
        xs[r][cq * 4 + 0] = x4.x; xs[r][cq * 4 + 1] = x4.y;
        xs[r][cq * 4 + 2] = x4.z; xs[r][cq * 4 + 3] = x4.w;
    }
    __syncthreads();
    const int tc = (tid & 15) * 4;
    const int tr = (tid >> 4) * 4;
    float acc[4][4];
    #pragma unroll
    for (int i = 0; i < 4; ++i)
        #pragma unroll
        for (int j = 0; j < 4; ++j) acc[i][j] = 0.f;
    #pragma unroll 4
    for (int k = 0; k < 64; ++k) {
        float xv[4], wv[4];
        #pragma unroll
        for (int i = 0; i < 4; ++i) xv[i] = xs[tr + i][k];
        #pragma unroll
        for (int j = 0; j < 4; ++j) wv[j] = ws[k][tc + j];
        #pragma unroll
        for (int i = 0; i < 4; ++i)
            #pragma unroll
            for (int j = 0; j < 4; ++j) acc[i][j] += xv[i] * wv[j];
    }
    #pragma unroll
    for (int i = 0; i < 4; ++i) {
        int node = node0 + tr + i;
        if (node < n_nodes) {
            float4 o = make_float4(acc[i][0] + root_b[tc + 0], acc[i][1] + root_b[tc + 1],
                                   acc[i][2] + root_b[tc + 2], acc[i][3] + root_b[tc + 3]);
            reinterpret_cast<float4*>(out)[node * 16 + (tc >> 2)] = o;
        }
    }
}

__global__ __launch_bounds__(256) void edge_direct_kernel(
    const float* __restrict__ x, const int* __restrict__ ei,
    const int* __restrict__ et, const float* __restrict__ weight,
    float* __restrict__ out, int n_edges)
{
    int gwave  = (int)((blockIdx.x * (long)blockDim.x + threadIdx.x) >> 6);
    int lane   = threadIdx.x & 63;
    int nwaves = (int)(((long)gridDim.x * blockDim.x) >> 6);
    for (int e = gwave; e < n_edges; e += nwaves) {
        int src  = ei[e];
        int dstn = ei[n_edges + e];
        int t    = et[e];
        float xv = x[src * 64 + lane];
        const float* __restrict__ W = weight + t * 4096;
        float acc = 0.f;
        #pragma unroll 8
        for (int k = 0; k < 64; ++k) {
            float xk = __shfl(xv, k);
            acc += xk * W[k * 64 + lane];
        }
        atomicAdd(&out[(long)dstn * 64 + lane], acc);
    }
}

extern "C" void kernel_launch(void* const* d_in, const int* in_sizes, int n_in,
                              void* d_out, int out_size, void* d_ws, size_t ws_size,
                              hipStream_t stream) {
    const float* x      = (const float*)d_in[0];
    const int*   ei     = (const int*)d_in[1];   // [2, E] int32
    const int*   et     = (const int*)d_in[2];   // [E]
    const float* weight = (const float*)d_in[3]; // [4, 64, 64]
    const float* root_w = (const float*)d_in[4]; // [64, 64]
    const float* root_b = (const float*)d_in[5]; // [64]
    float* out = (float*)d_out;

    const int n_nodes = in_sizes[0] / 64;
    const int n_edges = in_sizes[2];
    const int nb      = (n_nodes + 63) >> 6;

    int ssh = 1;
    while ((1 << ssh) < n_nodes) ++ssh;   // bits for src
    const int tsh = ssh + 6;              // 6 bits for local dst

    const size_t y_bytes  = (size_t)4 * n_nodes * 64 * sizeof(unsigned short);
    const size_t b_bytes  = y_bytes + ((size_t)3 * nb + 1 + n_edges) * 4;

    const int gf_blocks = (n_nodes + 255) / 256;

    if (nb <= NBMAX && tsh + 2 <= 32 && ws_size >= b_bytes) {
        unsigned short* y       = (unsigned short*)d_ws;
        int*            gcount  = (int*)((char*)d_ws + y_bytes);
        int*            offsets = gcount + nb;              // nb+1
        int*            cursor  = offsets + nb + 1;
        unsigned*       payload = (unsigned*)(cursor + nb);

        hipMemsetAsync(gcount, 0, (size_t)nb * 4, stream);
        hist_kernel<<<256, 256, 0, stream>>>(ei, gcount, n_edges, nb);
        scan_small_kernel<<<1, 1024, 0, stream>>>(gcount, offsets, cursor, nb);
        fillb_kernel<<<256, 256, 0, stream>>>(ei, et, cursor, payload,
                                              n_edges, nb, ssh, tsh);
        gemm_fused_kernel<<<gf_blocks, 256, 0, stream>>>(x, weight, root_w, root_b,
                                                         out, y, n_nodes);
        gatherb2_kernel<<<nb, 1024, 0, stream>>>(offsets, payload, y, out,
                                                 n_nodes, ssh, tsh);
    } else if (ws_size >= y_bytes) {
        unsigned short* y = (unsigned short*)d_ws;
        gemm_fused_kernel<<<gf_blocks, 256, 0, stream>>>(x, weight, root_w, root_b,
                                                         out, y, n_nodes);
        long total  = (long)n_edges * 16;
        int  blocks = (int)((total + 255) / 256);
        scatter_kernel<<<blocks, 256, 0, stream>>>(ei, et, y, out, n_edges, n_nodes);
    } else {
        gemm_root_kernel<<<(n_nodes + NT - 1) / NT, 256, 0, stream>>>(
            x, root_w, root_b, out, n_nodes);
        edge_direct_kernel<<<4096, 256, 0, stream>>>(x, ei, et, weight, out, n_edges);
    }
}

// Round 7
// 113.257 us; speedup vs baseline: 4.5611x; 1.1151x over previous
//
#include <hip/hip_runtime.h>

#define NT 64
#define NBMAX 4096   // max 64-node buckets for LDS-hist binning
#define CAPB 2048    // fixed payload slots per bucket (mean ~1279 here)

__device__ __forceinline__ unsigned short f2bf(float f) {
    unsigned u = __builtin_bit_cast(unsigned, f);
    unsigned r = (u + 0x7fffu + ((u >> 16) & 1u)) >> 16;   // round-nearest-even
    return (unsigned short)r;
}
__device__ __forceinline__ float bf2f(unsigned short h) {
    return __builtin_bit_cast(float, (unsigned)h << 16);
}

// ---------------------------------------------------------------------------
// Fused GEMM v2: 64-node tile, all 5 products per block (x staged once).
//   m in [0,3] -> y[m] = x @ weight[m]   (bf16, to workspace)
//   m == 4     -> out  = x @ root_w + b  (f32, initializes out)
// 256 threads: ng = tid&31 owns nodes {2ng, 2ng+1}; cg = tid>>5 owns 8 cols.
// ---------------------------------------------------------------------------
__global__ __launch_bounds__(256) void gemm_fused2_kernel(
    const float* __restrict__ x, const float* __restrict__ weight,
    const float* __restrict__ root_w, const float* __restrict__ root_b,
    float* __restrict__ out, unsigned short* __restrict__ y, int n_nodes)
{
    __shared__ unsigned short xsT[64][72];  // [k][node] bf16, row 144B
    __shared__ float ws[64][72];            // [k][col],  row 288B

    const int tid   = threadIdx.x;
    const int node0 = blockIdx.x * 64;

    // Stage x tile transposed as bf16 (1024 float4 loads, 4 per thread).
    #pragma unroll
    for (int i = 0; i < 4; ++i) {
        int v    = tid + i * 256;      // 0..1023 : 64 nodes x 16 quads
        int r    = v >> 4;
        int cq   = v & 15;
        int node = node0 + r;
        float4 x4 = (node < n_nodes)
                        ? reinterpret_cast<const float4*>(x)[(size_t)node * 16 + cq]
                        : make_float4(0.f, 0.f, 0.f, 0.f);
        xsT[cq * 4 + 0][r] = f2bf(x4.x);
        xsT[cq * 4 + 1][r] = f2bf(x4.y);
        xsT[cq * 4 + 2][r] = f2bf(x4.z);
        xsT[cq * 4 + 3][r] = f2bf(x4.w);
    }

    const int ng = tid & 31;       // node pair
    const int cg = tid >> 5;       // col group (8 cols)

    float bias[8];
    #pragma unroll
    for (int j = 0; j < 8; ++j) bias[j] = root_b[cg * 8 + j];

    for (int m = 0; m < 5; ++m) {
        const float* __restrict__ W = (m < 4) ? (weight + m * 4096) : root_w;
        __syncthreads();           // xsT visible (m=0) / prev ws readers done
        #pragma unroll
        for (int i = 0; i < 4; ++i) {
            int v  = tid + i * 256;    // 0..1023
            int r  = v >> 4;
            int cq = v & 15;
            float4 w4 = reinterpret_cast<const float4*>(W)[v];
            ws[r][cq * 4 + 0] = w4.x; ws[r][cq * 4 + 1] = w4.y;
            ws[r][cq * 4 + 2] = w4.z; ws[r][cq * 4 + 3] = w4.w;
        }
        __syncthreads();

        float acc[2][8];
        #pragma unroll
        for (int i = 0; i < 2; ++i)
            #pragma unroll
            for (int j = 0; j < 8; ++j) acc[i][j] = 0.f;

        #pragma unroll 4
        for (int k = 0; k < 64; ++k) {
            unsigned xu = *reinterpret_cast<const unsigned*>(&xsT[k][ng * 2]);
            float xv0 = __builtin_bit_cast(float, xu << 16);
            float xv1 = __builtin_bit_cast(float, xu & 0xffff0000u);
            float4 wa = *reinterpret_cast<const float4*>(&ws[k][cg * 8]);
            float4 wb = *reinterpret_cast<const float4*>(&ws[k][cg * 8 + 4]);
            float wv[8] = {wa.x, wa.y, wa.z, wa.w, wb.x, wb.y, wb.z, wb.w};
            #pragma unroll
            for (int j = 0; j < 8; ++j) {
                acc[0][j] += xv0 * wv[j];
                acc[1][j] += xv1 * wv[j];
            }
        }

        #pragma unroll
        for (int i = 0; i < 2; ++i) {
            int node = node0 + ng * 2 + i;
            if (node >= n_nodes) continue;
            if (m < 4) {
                uint4 o;
                o.x = (unsigned)f2bf(acc[i][0]) | ((unsigned)f2bf(acc[i][1]) << 16);
                o.y = (unsigned)f2bf(acc[i][2]) | ((unsigned)f2bf(acc[i][3]) << 16);
                o.z = (unsigned)f2bf(acc[i][4]) | ((unsigned)f2bf(acc[i][5]) << 16);
                o.w = (unsigned)f2bf(acc[i][6]) | ((unsigned)f2bf(acc[i][7]) << 16);
                *reinterpret_cast<uint4*>(
                    &y[((size_t)m * n_nodes + node) * 64 + cg * 8]) = o;
            } else {
                float4 oa = make_float4(acc[i][0] + bias[0], acc[i][1] + bias[1],
                                        acc[i][2] + bias[2], acc[i][3] + bias[3]);
                float4 ob = make_float4(acc[i][4] + bias[4], acc[i][5] + bias[5],
                                        acc[i][6] + bias[6], acc[i][7] + bias[7]);
                reinterpret_cast<float4*>(&out[(size_t)node * 64 + cg * 8])[0] = oa;
                reinterpret_cast<float4*>(&out[(size_t)node * 64 + cg * 8])[1] = ob;
            }
        }
    }
}

// ---------------------------------------------------------------------------
// Fill: bin edges into FIXED-capacity bucket slots (payload[b*CAPB + pos]).
// Per-block LDS hist -> one cursor atomic per (block,bucket) -> ranked writes.
// Overflow (pos >= CAPB): edge index pushed to spill list.
// payload = src | (dst&63)<<ssh | type<<tsh
// ---------------------------------------------------------------------------
__global__ __launch_bounds__(256) void fillb_kernel(
    const int* __restrict__ ei, const int* __restrict__ et,
    int* __restrict__ cursor, int* __restrict__ spill_cnt,
    int* __restrict__ spill, unsigned* __restrict__ payload,
    int n_edges, int nb, int ssh, int tsh)
{
    __shared__ int lh[NBMAX];
    __shared__ int lbase[NBMAX];
    const int chunk = (n_edges + gridDim.x - 1) / gridDim.x;
    const int lo = blockIdx.x * chunk;
    const int hi = min(lo + chunk, n_edges);
    for (int i = threadIdx.x; i < nb; i += 256) lh[i] = 0;
    __syncthreads();
    for (int e = lo + threadIdx.x; e < hi; e += 256)
        atomicAdd(&lh[ei[n_edges + e] >> 6], 1);
    __syncthreads();
    for (int i = threadIdx.x; i < nb; i += 256) {
        int c = lh[i];
        lbase[i] = c ? atomicAdd(&cursor[i], c) : 0;
        lh[i] = 0;
    }
    __syncthreads();
    for (int e = lo + threadIdx.x; e < hi; e += 256) {
        int src = ei[e];
        int d   = ei[n_edges + e];
        int t   = et[e];
        int b   = d >> 6;
        int r   = atomicAdd(&lh[b], 1);
        int pos = lbase[b] + r;
        if (pos < CAPB) {
            payload[(size_t)b * CAPB + pos] =
                (unsigned)src | ((unsigned)(d & 63) << ssh) | ((unsigned)t << tsh);
        } else {
            int sp = atomicAdd(spill_cnt, 1);
            spill[sp] = e;
        }
    }
}

// ---------------------------------------------------------------------------
// Gather (bf16 y): one 1024-thread block per bucket.
//   Phase 1: in-LDS counting sort of the bucket's payload by local dst.
//   Phase 2: 64 groups x 16 threads; group g owns node b*64+g, register acc.
// ---------------------------------------------------------------------------
__global__ __launch_bounds__(1024) void gatherb2_kernel(
    const int* __restrict__ cursor, const unsigned* __restrict__ payload,
    const unsigned short* __restrict__ y, float* __restrict__ out,
    int n_nodes, int ssh, int tsh)
{
    __shared__ unsigned raw[CAPB];
    __shared__ unsigned srt[CAPB];
    __shared__ int hist[64];
    __shared__ int hoff[65];

    const int tid = threadIdx.x;
    const int b   = blockIdx.x;
    const int n_in = min(cursor[b], CAPB);
    const unsigned* __restrict__ pl_base = payload + (size_t)b * CAPB;

    if (tid < 64) hist[tid] = 0;
    __syncthreads();
    for (int i = tid; i < n_in; i += 1024) {
        unsigned pl = pl_base[i];
        raw[i] = pl;
        atomicAdd(&hist[(pl >> ssh) & 63], 1);
    }
    __syncthreads();
    if (tid < 64) {                       // wave-parallel exclusive scan, 64 bins
        int v = hist[tid];
        int s = v;
        #pragma unroll
        for (int d = 1; d < 64; d <<= 1) {
            int u = __shfl_up(s, d, 64);
            if (tid >= d) s += u;
        }
        hoff[tid] = s - v;
        if (tid == 63) hoff[64] = s;
        hist[tid] = 0;
    }
    __syncthreads();
    for (int i = tid; i < n_in; i += 1024) {
        unsigned pl = raw[i];
        int l = (pl >> ssh) & 63;
        int r = atomicAdd(&hist[l], 1);
        srt[hoff[l] + r] = pl;
    }
    __syncthreads();

    const int g    = tid >> 4;            // node row within bucket
    const int cq   = tid & 15;            // channel quad
    const int node = b * 64 + g;
    const unsigned smask = (1u << ssh) - 1;

    float4 acc = make_float4(0.f, 0.f, 0.f, 0.f);
    const int s0 = hoff[g];
    const int s1 = hoff[g + 1];
    for (int p = s0; p < s1; ++p) {
        unsigned pl = srt[p];
        int src = (int)(pl & smask);
        int t   = (int)(pl >> tsh);
        ushort4 v = reinterpret_cast<const ushort4*>(y)[((long)t * n_nodes + src) * 16 + cq];
        acc.x += bf2f(v.x); acc.y += bf2f(v.y);
        acc.z += bf2f(v.z); acc.w += bf2f(v.w);
    }
    if (node < n_nodes) {
        float4* o  = reinterpret_cast<float4*>(out) + (long)node * 16 + cq;
        float4 cur = *o;
        cur.x += acc.x; cur.y += acc.y; cur.z += acc.z; cur.w += acc.w;
        *o = cur;
    }
}

// Drain overflow spill list (normally empty). Runs after gather.
__global__ __launch_bounds__(256) void spill_kernel(
    const int* __restrict__ ei, const int* __restrict__ et,
    const int* __restrict__ spill_cnt, const int* __restrict__ spill,
    const unsigned short* __restrict__ y, float* __restrict__ out,
    int n_edges, int n_nodes)
{
    const int n = *spill_cnt;
    const long total  = (long)n * 16;
    const long stride = (long)gridDim.x * 256;
    for (long i = blockIdx.x * 256 + threadIdx.x; i < total; i += stride) {
        int e  = spill[i >> 4];
        int cq = (int)(i & 15);
        int src  = ei[e];
        int dstn = ei[n_edges + e];
        int t    = et[e];
        ushort4 v = reinterpret_cast<const ushort4*>(y)[((long)t * n_nodes + src) * 16 + cq];
        float* o = out + (long)dstn * 64 + cq * 4;
        atomicAdd(o + 0, bf2f(v.x));
        atomicAdd(o + 1, bf2f(v.y));
        atomicAdd(o + 2, bf2f(v.z));
        atomicAdd(o + 3, bf2f(v.w));
    }
}

// --------------------- fallbacks (small workspace) -------------------------
__global__ __launch_bounds__(256) void scatter_kernel(
    const int* __restrict__ ei, const int* __restrict__ et,
    const unsigned short* __restrict__ y, float* __restrict__ out,
    int n_edges, int n_nodes)
{
    long idx = (long)blockIdx.x * blockDim.x + threadIdx.x;
    if (idx >= (long)n_edges * 16) return;
    int e  = (int)(idx >> 4);
    int cq = (int)(idx & 15);
    int src  = ei[e];
    int dstn = ei[n_edges + e];
    int t    = et[e];
    ushort4 v = reinterpret_cast<const ushort4*>(y)[((long)t * n_nodes + src) * 16 + cq];
    float* o = out + (long)dstn * 64 + cq * 4;
    atomicAdd(o + 0, bf2f(v.x));
    atomicAdd(o + 1, bf2f(v.y));
    atomicAdd(o + 2, bf2f(v.z));
    atomicAdd(o + 3, bf2f(v.w));
}

__global__ __launch_bounds__(256) void gemm_root_kernel(
    const float* __restrict__ x, const float* __restrict__ root_w,
    const float* __restrict__ root_b, float* __restrict__ out, int n_nodes)
{
    __shared__ float xs[NT][65];
    __shared__ float ws[64][65];
    const int tid   = threadIdx.x;
    const int node0 = blockIdx.x * NT;
    #pragma unroll
    for (int i = 0; i < 4; ++i) {
        int v  = tid + i * 256;
        int r  = v >> 4;
        int cq = v & 15;
        float4 w4 = reinterpret_cast<const float4*>(root_w)[v];
        ws[r][cq * 4 + 0] = w4.x; ws[r][cq * 4 + 1] = w4.y;
        ws[r][cq * 4 + 2] = w4.z; ws[r][cq * 4 + 3] = w4.w;
        int node = node0 + r;
        float4 x4 = (node < n_nodes)
                        ? reinterpret_cast<const float4*>(x)[node * 16 + cq]
                        : make_float4(0.f, 0.f, 0.f, 0.f);
        xs[r][cq * 4 + 0] = x4.x; xs[r][cq * 4 + 1] = x4.y;
        xs[r][cq * 4 + 2] = x4.z; xs[r][cq * 4 + 3] = x4.w;
    }
    __syncthreads();
    const int tc = (tid & 15) * 4;
    const int tr = (tid >> 4) * 4;
    float acc[4][4];
    #pragma unroll
    for (int i = 0; i < 4; ++i)
        #pragma unroll
        for (int j = 0; j < 4; ++j) acc[i][j] = 0.f;
    #pragma unroll 4
    for (int k = 0; k < 64; ++k) {
        float xv[4], wv[4];
        #pragma unroll
        for (int i = 0; i < 4; ++i) xv[i] = xs[tr + i][k];
        #pragma unroll
        for (int j = 0; j < 4; ++j) wv[j] = ws[k][tc + j];
        #pragma unroll
        for (int i = 0; i < 4; ++i)
            #pragma unroll
            for (int j = 0; j < 4; ++j) acc[i][j] += xv[i] * wv[j];
    }
    #pragma unroll
    for (int i = 0; i < 4; ++i) {
        int node = node0 + tr + i;
        if (node < n_nodes) {
            float4 o = make_float4(acc[i][0] + root_b[tc + 0], acc[i][1] + root_b[tc + 1],
                                   acc[i][2] + root_b[tc + 2], acc[i][3] + root_b[tc + 3]);
            reinterpret_cast<float4*>(out)[node * 16 + (tc >> 2)] = o;
        }
    }
}

__global__ __launch_bounds__(256) void edge_direct_kernel(
    const float* __restrict__ x, const int* __restrict__ ei,
    const int* __restrict__ et, const float* __restrict__ weight,
    float* __restrict__ out, int n_edges)
{
    int gwave  = (int)((blockIdx.x * (long)blockDim.x + threadIdx.x) >> 6);
    int lane   = threadIdx.x & 63;
    int nwaves = (int)(((long)gridDim.x * blockDim.x) >> 6);
    for (int e = gwave; e < n_edges; e += nwaves) {
        int src  = ei[e];
        int dstn = ei[n_edges + e];
        int t    = et[e];
        float xv = x[src * 64 + lane];
        const float* __restrict__ W = weight + t * 4096;
        float acc = 0.f;
        #pragma unroll 8
        for (int k = 0; k < 64; ++k) {
            float xk = __shfl(xv, k);
            acc += xk * W[k * 64 + lane];
        }
        atomicAdd(&out[(long)dstn * 64 + lane], acc);
    }
}

extern "C" void kernel_launch(void* const* d_in, const int* in_sizes, int n_in,
                              void* d_out, int out_size, void* d_ws, size_t ws_size,
                              hipStream_t stream) {
    const float* x      = (const float*)d_in[0];
    const int*   ei     = (const int*)d_in[1];   // [2, E] int32
    const int*   et     = (const int*)d_in[2];   // [E]
    const float* weight = (const float*)d_in[3]; // [4, 64, 64]
    const float* root_w = (const float*)d_in[4]; // [64, 64]
    const float* root_b = (const float*)d_in[5]; // [64]
    float* out = (float*)d_out;

    const int n_nodes = in_sizes[0] / 64;
    const int n_edges = in_sizes[2];
    const int nb      = (n_nodes + 63) >> 6;

    int ssh = 1;
    while ((1 << ssh) < n_nodes) ++ssh;   // bits for src
    const int tsh = ssh + 6;              // 6 bits for local dst

    const size_t y_bytes = (size_t)4 * n_nodes * 64 * sizeof(unsigned short);
    const size_t b_bytes = y_bytes +
        ((size_t)nb + 1 + (size_t)nb * CAPB + n_edges) * 4;

    const int gf_blocks = (n_nodes + 63) / 64;

    if (nb <= NBMAX && tsh + 2 <= 32 && ws_size >= b_bytes) {
        unsigned short* y         = (unsigned short*)d_ws;
        int*            cursor    = (int*)((char*)d_ws + y_bytes);   // nb
        int*            spill_cnt = cursor + nb;                     // 1
        unsigned*       payload   = (unsigned*)(spill_cnt + 1);      // nb*CAPB
        int*            spill     = (int*)(payload + (size_t)nb * CAPB);

        hipMemsetAsync(cursor, 0, (size_t)(nb + 1) * 4, stream);
        fillb_kernel<<<256, 256, 0, stream>>>(ei, et, cursor, spill_cnt, spill,
                                              payload, n_edges, nb, ssh, tsh);
        gemm_fused2_kernel<<<gf_blocks, 256, 0, stream>>>(x, weight, root_w, root_b,
                                                          out, y, n_nodes);
        gatherb2_kernel<<<nb, 1024, 0, stream>>>(cursor, payload, y, out,
                                                 n_nodes, ssh, tsh);
        spill_kernel<<<64, 256, 0, stream>>>(ei, et, spill_cnt, spill, y, out,
                                             n_edges, n_nodes);
    } else if (ws_size >= y_bytes) {
        unsigned short* y = (unsigned short*)d_ws;
        gemm_fused2_kernel<<<gf_blocks, 256, 0, stream>>>(x, weight, root_w, root_b,
                                                          out, y, n_nodes);
        long total  = (long)n_edges * 16;
        int  blocks = (int)((total + 255) / 256);
        scatter_kernel<<<blocks, 256, 0, stream>>>(ei, et, y, out, n_edges, n_nodes);
    } else {
        gemm_root_kernel<<<(n_nodes + NT - 1) / NT, 256, 0, stream>>>(
            x, root_w, root_b, out, n_nodes);
        edge_direct_kernel<<<4096, 256, 0, stream>>>(x, ei, et, weight, out, n_edges);
    }
}

// Round 8
// 88.698 us; speedup vs baseline: 5.8240x; 1.2769x over previous
//
#include <hip/hip_runtime.h>

#define NT 64
#define NBMAX 4096   // max 64-node buckets for LDS-hist binning
#define CAPB 2048    // fixed payload slots per bucket (mean ~1279 here)

typedef short bf16x8 __attribute__((ext_vector_type(8)));
typedef float f32x4  __attribute__((ext_vector_type(4)));

__device__ __forceinline__ unsigned short f2bf(float f) {
    unsigned u = __builtin_bit_cast(unsigned, f);
    unsigned r = (u + 0x7fffu + ((u >> 16) & 1u)) >> 16;   // round-nearest-even
    return (unsigned short)r;
}
__device__ __forceinline__ float bf2f(unsigned short h) {
    return __builtin_bit_cast(float, (unsigned)h << 16);
}
__device__ __forceinline__ unsigned pack2(float a, float b) {
    return (unsigned)f2bf(a) | ((unsigned)f2bf(b) << 16);
}

// ---------------------------------------------------------------------------
// Prep: W (4x64x64 f32) + root_w -> bf16, transposed [m][col][k], XOR-swizzled
// ( byte ^= (col&7)<<4 within each 128B row ) — the exact LDS image gemm wants.
// ---------------------------------------------------------------------------
__global__ __launch_bounds__(256) void prep_w_kernel(
    const float* __restrict__ weight, const float* __restrict__ root_w,
    unsigned short* __restrict__ wt)
{
    int g = blockIdx.x * 256 + threadIdx.x;
    if (g >= 5 * 4096) return;
    int m = g >> 12, rem = g & 4095, c = rem >> 6, k = rem & 63;
    float v = (m < 4) ? weight[m * 4096 + k * 64 + c] : root_w[k * 64 + c];
    int byte = m * 8192 + c * 128 + ((k * 2) ^ ((c & 7) << 4));
    wt[byte >> 1] = f2bf(v);
}

// ---------------------------------------------------------------------------
// MFMA GEMM: 64-node tile, all 5 products per block, one barrier.
//   m in [0,3] -> y[m] = x @ weight[m]   (bf16)
//   m == 4     -> out  = x @ root_w + b  (f32, initializes out)
// LDS image: [0,8KB): x tile row-major bf16 swizzled; [8KB,48KB): Wt (5 mats).
// Wave wv owns nodes wv*16..+15; 4 col-tiles of 16; K=64 as 2 MFMA k-steps.
// ---------------------------------------------------------------------------
__global__ __launch_bounds__(256) void gemm_mfma_kernel(
    const float* __restrict__ x, const uint4* __restrict__ wt4,
    const float* __restrict__ root_b,
    float* __restrict__ out, unsigned short* __restrict__ y, int n_nodes)
{
    __shared__ uint4 lds4[3072];   // 48 KB

    const int tid   = threadIdx.x;
    const int node0 = blockIdx.x * 64;

    // Stage all 5 Wt (pre-swizzled in global -> linear copy).
    for (int i = tid; i < 2560; i += 256) lds4[512 + i] = wt4[i];

    // Stage x tile: thread -> node n = tid>>2, k-chunk kq = tid&3 (16 elems).
    {
        int n    = tid >> 2;
        int kq   = tid & 3;
        int node = node0 + n;
        uint4 p0, p1;
        if (node < n_nodes) {
            const float4* src = reinterpret_cast<const float4*>(x)
                                + (size_t)node * 16 + kq * 4;
            float4 f0 = src[0], f1 = src[1], f2 = src[2], f3 = src[3];
            p0.x = pack2(f0.x, f0.y); p0.y = pack2(f0.z, f0.w);
            p0.z = pack2(f1.x, f1.y); p0.w = pack2(f1.z, f1.w);
            p1.x = pack2(f2.x, f2.y); p1.y = pack2(f2.z, f2.w);
            p1.z = pack2(f3.x, f3.y); p1.w = pack2(f3.z, f3.w);
        } else {
            p0 = make_uint4(0, 0, 0, 0);
            p1 = p0;
        }
        int s0 = (kq * 2) ^ (n & 7);
        lds4[n * 8 + s0]       = p0;
        lds4[n * 8 + (s0 ^ 1)] = p1;
    }
    __syncthreads();

    const int wv = tid >> 6;
    const int l  = tid & 63;
    const int lo = l & 15;
    const int hi = l >> 4;

    // A fragments (m-invariant): row = wv*16+lo, k = ks*32 + hi*8 .. +7
    const int arow = wv * 16 + lo;
    bf16x8 a0 = *reinterpret_cast<const bf16x8*>(
        &lds4[arow * 8 + ((0 + hi) ^ (arow & 7))]);
    bf16x8 a1 = *reinterpret_cast<const bf16x8*>(
        &lds4[arow * 8 + ((4 + hi) ^ (arow & 7))]);

    for (int m = 0; m < 5; ++m) {
        f32x4 acc[4];
        #pragma unroll
        for (int ct = 0; ct < 4; ++ct)
            acc[ct] = (f32x4){0.f, 0.f, 0.f, 0.f};

        #pragma unroll
        for (int ct = 0; ct < 4; ++ct) {
            int c     = ct * 16 + lo;
            int bbase = 512 + m * 512 + c * 8;
            bf16x8 b0 = *reinterpret_cast<const bf16x8*>(
                &lds4[bbase + ((0 + hi) ^ (c & 7))]);
            acc[ct] = __builtin_amdgcn_mfma_f32_16x16x32_bf16(a0, b0, acc[ct], 0, 0, 0);
            bf16x8 b1 = *reinterpret_cast<const bf16x8*>(
                &lds4[bbase + ((4 + hi) ^ (c & 7))]);
            acc[ct] = __builtin_amdgcn_mfma_f32_16x16x32_bf16(a1, b1, acc[ct], 0, 0, 0);
        }

        if (m < 4) {
            unsigned short* __restrict__ ym = y + (size_t)m * n_nodes * 64;
            #pragma unroll
            for (int ct = 0; ct < 4; ++ct) {
                int col = ct * 16 + lo;
                #pragma unroll
                for (int r = 0; r < 4; ++r) {
                    int node = node0 + wv * 16 + hi * 4 + r;
                    if (node < n_nodes)
                        ym[(size_t)node * 64 + col] = f2bf(acc[ct][r]);
                }
            }
        } else {
            #pragma unroll
            for (int ct = 0; ct < 4; ++ct) {
                int col = ct * 16 + lo;
                float rb = root_b[col];
                #pragma unroll
                for (int r = 0; r < 4; ++r) {
                    int node = node0 + wv * 16 + hi * 4 + r;
                    if (node < n_nodes)
                        out[(size_t)node * 64 + col] = acc[ct][r] + rb;
                }
            }
        }
    }
}

// ---------------------------------------------------------------------------
// Fill: bin edges into FIXED-capacity bucket slots (payload[b*CAPB + pos]).
// payload = src | (dst&63)<<ssh | type<<tsh
// ---------------------------------------------------------------------------
__global__ __launch_bounds__(256) void fillb_kernel(
    const int* __restrict__ ei, const int* __restrict__ et,
    int* __restrict__ cursor, int* __restrict__ spill_cnt,
    int* __restrict__ spill, unsigned* __restrict__ payload,
    int n_edges, int nb, int ssh, int tsh)
{
    __shared__ int lh[NBMAX];
    __shared__ int lbase[NBMAX];
    const int chunk = (n_edges + gridDim.x - 1) / gridDim.x;
    const int lo = blockIdx.x * chunk;
    const int hi = min(lo + chunk, n_edges);
    for (int i = threadIdx.x; i < nb; i += 256) lh[i] = 0;
    __syncthreads();
    for (int e = lo + threadIdx.x; e < hi; e += 256)
        atomicAdd(&lh[ei[n_edges + e] >> 6], 1);
    __syncthreads();
    for (int i = threadIdx.x; i < nb; i += 256) {
        int c = lh[i];
        lbase[i] = c ? atomicAdd(&cursor[i], c) : 0;
        lh[i] = 0;
    }
    __syncthreads();
    for (int e = lo + threadIdx.x; e < hi; e += 256) {
        int src = ei[e];
        int d   = ei[n_edges + e];
        int t   = et[e];
        int b   = d >> 6;
        int r   = atomicAdd(&lh[b], 1);
        int pos = lbase[b] + r;
        if (pos < CAPB) {
            payload[(size_t)b * CAPB + pos] =
                (unsigned)src | ((unsigned)(d & 63) << ssh) | ((unsigned)t << tsh);
        } else {
            int sp = atomicAdd(spill_cnt, 1);
            spill[sp] = e;
        }
    }
}

// ---------------------------------------------------------------------------
// Gather (bf16 y): one 1024-thread block per bucket; in-LDS counting sort by
// local dst, then 64 groups x 16 threads accumulate in registers. No atomics.
// ---------------------------------------------------------------------------
__global__ __launch_bounds__(1024) void gatherb2_kernel(
    const int* __restrict__ cursor, const unsigned* __restrict__ payload,
    const unsigned short* __restrict__ y, float* __restrict__ out,
    int n_nodes, int ssh, int tsh)
{
    __shared__ unsigned raw[CAPB];
    __shared__ unsigned srt[CAPB];
    __shared__ int hist[64];
    __shared__ int hoff[65];

    const int tid = threadIdx.x;
    const int b   = blockIdx.x;
    const int n_in = min(cursor[b], CAPB);
    const unsigned* __restrict__ pl_base = payload + (size_t)b * CAPB;

    if (tid < 64) hist[tid] = 0;
    __syncthreads();
    for (int i = tid; i < n_in; i += 1024) {
        unsigned pl = pl_base[i];
        raw[i] = pl;
        atomicAdd(&hist[(pl >> ssh) & 63], 1);
    }
    __syncthreads();
    if (tid < 64) {                       // wave-parallel exclusive scan
        int v = hist[tid];
        int s = v;
        #pragma unroll
        for (int d = 1; d < 64; d <<= 1) {
            int u = __shfl_up(s, d, 64);
            if (tid >= d) s += u;
        }
        hoff[tid] = s - v;
        if (tid == 63) hoff[64] = s;
        hist[tid] = 0;
    }
    __syncthreads();
    for (int i = tid; i < n_in; i += 1024) {
        unsigned pl = raw[i];
        int lnode = (pl >> ssh) & 63;
        int r = atomicAdd(&hist[lnode], 1);
        srt[hoff[lnode] + r] = pl;
    }
    __syncthreads();

    const int g    = tid >> 4;
    const int cq   = tid & 15;
    const int node = b * 64 + g;
    const unsigned smask = (1u << ssh) - 1;

    float4 acc = make_float4(0.f, 0.f, 0.f, 0.f);
    const int s0 = hoff[g];
    const int s1 = hoff[g + 1];
    for (int p = s0; p < s1; ++p) {
        unsigned pl = srt[p];
        int src = (int)(pl & smask);
        int t   = (int)(pl >> tsh);
        ushort4 v = reinterpret_cast<const ushort4*>(y)[((long)t * n_nodes + src) * 16 + cq];
        acc.x += bf2f(v.x); acc.y += bf2f(v.y);
        acc.z += bf2f(v.z); acc.w += bf2f(v.w);
    }
    if (node < n_nodes) {
        float4* o  = reinterpret_cast<float4*>(out) + (long)node * 16 + cq;
        float4 cur = *o;
        cur.x += acc.x; cur.y += acc.y; cur.z += acc.z; cur.w += acc.w;
        *o = cur;
    }
}

// Drain overflow spill list (normally empty).
__global__ __launch_bounds__(256) void spill_kernel(
    const int* __restrict__ ei, const int* __restrict__ et,
    const int* __restrict__ spill_cnt, const int* __restrict__ spill,
    const unsigned short* __restrict__ y, float* __restrict__ out,
    int n_edges, int n_nodes)
{
    const int n = *spill_cnt;
    const long total  = (long)n * 16;
    const long stride = (long)gridDim.x * 256;
    for (long i = blockIdx.x * 256 + threadIdx.x; i < total; i += stride) {
        int e  = spill[i >> 4];
        int cq = (int)(i & 15);
        int src  = ei[e];
        int dstn = ei[n_edges + e];
        int t    = et[e];
        ushort4 v = reinterpret_cast<const ushort4*>(y)[((long)t * n_nodes + src) * 16 + cq];
        float* o = out + (long)dstn * 64 + cq * 4;
        atomicAdd(o + 0, bf2f(v.x));
        atomicAdd(o + 1, bf2f(v.y));
        atomicAdd(o + 2, bf2f(v.z));
        atomicAdd(o + 3, bf2f(v.w));
    }
}

// --------------------- fallbacks (small workspace) -------------------------
__global__ __launch_bounds__(256) void gemm_fused2_kernel(
    const float* __restrict__ x, const float* __restrict__ weight,
    const float* __restrict__ root_w, const float* __restrict__ root_b,
    float* __restrict__ out, unsigned short* __restrict__ y, int n_nodes)
{
    __shared__ unsigned short xsT[64][72];
    __shared__ float ws[64][72];
    const int tid   = threadIdx.x;
    const int node0 = blockIdx.x * 64;
    #pragma unroll
    for (int i = 0; i < 4; ++i) {
        int v    = tid + i * 256;
        int r    = v >> 4;
        int cq   = v & 15;
        int node = node0 + r;
        float4 x4 = (node < n_nodes)
                        ? reinterpret_cast<const float4*>(x)[(size_t)node * 16 + cq]
                        : make_float4(0.f, 0.f, 0.f, 0.f);
        xsT[cq * 4 + 0][r] = f2bf(x4.x);
        xsT[cq * 4 + 1][r] = f2bf(x4.y);
        xsT[cq * 4 + 2][r] = f2bf(x4.z);
        xsT[cq * 4 + 3][r] = f2bf(x4.w);
    }
    const int ng = tid & 31;
    const int cg = tid >> 5;
    float bias[8];
    #pragma unroll
    for (int j = 0; j < 8; ++j) bias[j] = root_b[cg * 8 + j];
    for (int m = 0; m < 5; ++m) {
        const float* __restrict__ W = (m < 4) ? (weight + m * 4096) : root_w;
        __syncthreads();
        #pragma unroll
        for (int i = 0; i < 4; ++i) {
            int v  = tid + i * 256;
            int r  = v >> 4;
            int cq = v & 15;
            float4 w4 = reinterpret_cast<const float4*>(W)[v];
            ws[r][cq * 4 + 0] = w4.x; ws[r][cq * 4 + 1] = w4.y;
            ws[r][cq * 4 + 2] = w4.z; ws[r][cq * 4 + 3] = w4.w;
        }
        __syncthreads();
        float acc[2][8];
        #pragma unroll
        for (int i = 0; i < 2; ++i)
            #pragma unroll
            for (int j = 0; j < 8; ++j) acc[i][j] = 0.f;
        #pragma unroll 4
        for (int k = 0; k < 64; ++k) {
            unsigned xu = *reinterpret_cast<const unsigned*>(&xsT[k][ng * 2]);
            float xv0 = __builtin_bit_cast(float, xu << 16);
            float xv1 = __builtin_bit_cast(float, xu & 0xffff0000u);
            float4 wa = *reinterpret_cast<const float4*>(&ws[k][cg * 8]);
            float4 wb = *reinterpret_cast<const float4*>(&ws[k][cg * 8 + 4]);
            float wv[8] = {wa.x, wa.y, wa.z, wa.w, wb.x, wb.y, wb.z, wb.w};
            #pragma unroll
            for (int j = 0; j < 8; ++j) {
                acc[0][j] += xv0 * wv[j];
                acc[1][j] += xv1 * wv[j];
            }
        }
        #pragma unroll
        for (int i = 0; i < 2; ++i) {
            int node = node0 + ng * 2 + i;
            if (node >= n_nodes) continue;
            if (m < 4) {
                uint4 o;
                o.x = pack2(acc[i][0], acc[i][1]);
                o.y = pack2(acc[i][2], acc[i][3]);
                o.z = pack2(acc[i][4], acc[i][5]);
                o.w = pack2(acc[i][6], acc[i][7]);
                *reinterpret_cast<uint4*>(
                    &y[((size_t)m * n_nodes + node) * 64 + cg * 8]) = o;
            } else {
                float4 oa = make_float4(acc[i][0] + bias[0], acc[i][1] + bias[1],
                                        acc[i][2] + bias[2], acc[i][3] + bias[3]);
                float4 ob = make_float4(acc[i][4] + bias[4], acc[i][5] + bias[5],
                                        acc[i][6] + bias[6], acc[i][7] + bias[7]);
                reinterpret_cast<float4*>(&out[(size_t)node * 64 + cg * 8])[0] = oa;
                reinterpret_cast<float4*>(&out[(size_t)node * 64 + cg * 8])[1] = ob;
            }
        }
    }
}

__global__ __launch_bounds__(256) void scatter_kernel(
    const int* __restrict__ ei, const int* __restrict__ et,
    const unsigned short* __restrict__ y, float* __restrict__ out,
    int n_edges, int n_nodes)
{
    long idx = (long)blockIdx.x * blockDim.x + threadIdx.x;
    if (idx >= (long)n_edges * 16) return;
    int e  = (int)(idx >> 4);
    int cq = (int)(idx & 15);
    int src  = ei[e];
    int dstn = ei[n_edges + e];
    int t    = et[e];
    ushort4 v = reinterpret_cast<const ushort4*>(y)[((long)t * n_nodes + src) * 16 + cq];
    float* o = out + (long)dstn * 64 + cq * 4;
    atomicAdd(o + 0, bf2f(v.x));
    atomicAdd(o + 1, bf2f(v.y));
    atomicAdd(o + 2, bf2f(v.z));
    atomicAdd(o + 3, bf2f(v.w));
}

__global__ __launch_bounds__(256) void gemm_root_kernel(
    const float* __restrict__ x, const float* __restrict__ root_w,
    const float* __restrict__ root_b, float* __restrict__ out, int n_nodes)
{
    __shared__ float xs[NT][65];
    __shared__ float ws[64][65];
    const int tid   = threadIdx.x;
    const int node0 = blockIdx.x * NT;
    #pragma unroll
    for (int i = 0; i < 4; ++i) {
        int v  = tid + i * 256;
        int r  = v >> 4;
        int cq = v & 15;
        float4 w4 = reinterpret_cast<const float4*>(root_w)[v];
        ws[r][cq * 4 + 0] = w4.x; ws[r][cq * 4 + 1] = w4.y;
        ws[r][cq * 4 + 2] = w4.z; ws[r][cq * 4 + 3] = w4.w;
        int node = node0 + r;
        float4 x4 = (node < n_nodes)
                        ? reinterpret_cast<const float4*>(x)[node * 16 + cq]
                        : make_float4(0.f, 0.f, 0.f, 0.f);
        xs[r][cq * 4 + 0] = x4.x; xs[r][cq * 4 + 1] = x4.y;
        xs[r][cq * 4 + 2] = x4.z; xs[r][cq * 4 + 3] = x4.w;
    }
    __syncthreads();
    const int tc = (tid & 15) * 4;
    const int tr = (tid >> 4) * 4;
    float acc[4][4];
    #pragma unroll
    for (int i = 0; i < 4; ++i)
        #pragma unroll
        for (int j = 0; j < 4; ++j) acc[i][j] = 0.f;
    #pragma unroll 4
    for (int k = 0; k < 64; ++k) {
        float xv[4], wv[4];
        #pragma unroll
        for (int i = 0; i < 4; ++i) xv[i] = xs[tr + i][k];
        #pragma unroll
        for (int j = 0; j < 4; ++j) wv[j] = ws[k][tc + j];
        #pragma unroll
        for (int i = 0; i < 4; ++i)
            #pragma unroll
            for (int j = 0; j < 4; ++j) acc[i][j] += xv[i] * wv[j];
    }
    #pragma unroll
    for (int i = 0; i < 4; ++i) {
        int node = node0 + tr + i;
        if (node < n_nodes) {
            float4 o = make_float4(acc[i][0] + root_b[tc + 0], acc[i][1] + root_b[tc + 1],
                                   acc[i][2] + root_b[tc + 2], acc[i][3] + root_b[tc + 3]);
            reinterpret_cast<float4*>(out)[node * 16 + (tc >> 2)] = o;
        }
    }
}

__global__ __launch_bounds__(256) void edge_direct_kernel(
    const float* __restrict__ x, const int* __restrict__ ei,
    const int* __restrict__ et, const float* __restrict__ weight,
    float* __restrict__ out, int n_edges)
{
    int gwave  = (int)((blockIdx.x * (long)blockDim.x + threadIdx.x) >> 6);
    int lane   = threadIdx.x & 63;
    int nwaves = (int)(((long)gridDim.x * blockDim.x) >> 6);
    for (int e = gwave; e < n_edges; e += nwaves) {
        int src  = ei[e];
        int dstn = ei[n_edges + e];
        int t    = et[e];
        float xv = x[src * 64 + lane];
        const float* __restrict__ W = weight + t * 4096;
        float acc = 0.f;
        #pragma unroll 8
        for (int k = 0; k < 64; ++k) {
            float xk = __shfl(xv, k);
            acc += xk * W[k * 64 + lane];
        }
        atomicAdd(&out[(long)dstn * 64 + lane], acc);
    }
}

extern "C" void kernel_launch(void* const* d_in, const int* in_sizes, int n_in,
                              void* d_out, int out_size, void* d_ws, size_t ws_size,
                              hipStream_t stream) {
    const float* x      = (const float*)d_in[0];
    const int*   ei     = (const int*)d_in[1];   // [2, E] int32
    const int*   et     = (const int*)d_in[2];   // [E]
    const float* weight = (const float*)d_in[3]; // [4, 64, 64]
    const float* root_w = (const float*)d_in[4]; // [64, 64]
    const float* root_b = (const float*)d_in[5]; // [64]
    float* out = (float*)d_out;

    const int n_nodes = in_sizes[0] / 64;
    const int n_edges = in_sizes[2];
    const int nb      = (n_nodes + 63) >> 6;

    int ssh = 1;
    while ((1 << ssh) < n_nodes) ++ssh;   // bits for src
    const int tsh = ssh + 6;              // 6 bits for local dst

    const size_t wt_bytes = 5 * 4096 * sizeof(unsigned short);   // 40 KB
    const size_t y_bytes  = (size_t)4 * n_nodes * 64 * sizeof(unsigned short);
    const size_t b_bytes  = wt_bytes + y_bytes +
        ((size_t)nb + 1 + (size_t)nb * CAPB + n_edges) * 4;

    if (nb <= NBMAX && tsh + 2 <= 32 && ws_size >= b_bytes) {
        unsigned short* wt        = (unsigned short*)d_ws;
        unsigned short* y         = (unsigned short*)((char*)d_ws + wt_bytes);
        int*            cursor    = (int*)((char*)d_ws + wt_bytes + y_bytes);
        int*            spill_cnt = cursor + nb;
        unsigned*       payload   = (unsigned*)(spill_cnt + 1);
        int*            spill     = (int*)(payload + (size_t)nb * CAPB);

        prep_w_kernel<<<80, 256, 0, stream>>>(weight, root_w, wt);
        hipMemsetAsync(cursor, 0, (size_t)(nb + 1) * 4, stream);
        fillb_kernel<<<256, 256, 0, stream>>>(ei, et, cursor, spill_cnt, spill,
                                              payload, n_edges, nb, ssh, tsh);
        gemm_mfma_kernel<<<nb, 256, 0, stream>>>(x, (const uint4*)wt, root_b,
                                                 out, y, n_nodes);
        gatherb2_kernel<<<nb, 1024, 0, stream>>>(cursor, payload, y, out,
                                                 n_nodes, ssh, tsh);
        spill_kernel<<<64, 256, 0, stream>>>(ei, et, spill_cnt, spill, y, out,
                                             n_edges, n_nodes);
    } else if (ws_size >= y_bytes) {
        unsigned short* y = (unsigned short*)d_ws;
        gemm_fused2_kernel<<<(n_nodes + 63) / 64, 256, 0, stream>>>(
            x, weight, root_w, root_b, out, y, n_nodes);
        long total  = (long)n_edges * 16;
        int  blocks = (int)((total + 255) / 256);
        scatter_kernel<<<blocks, 256, 0, stream>>>(ei, et, y, out, n_edges, n_nodes);
    } else {
        gemm_root_kernel<<<(n_nodes + NT - 1) / NT, 256, 0, stream>>>(
            x, root_w, root_b, out, n_nodes);
        edge_direct_kernel<<<4096, 256, 0, stream>>>(x, ei, et, weight, out, n_edges);
    }
}

// Round 9
// 84.895 us; speedup vs baseline: 6.0849x; 1.0448x over previous
//
#include <hip/hip_runtime.h>

#define NT 64
#define NBMAX 4096   // max 64-node buckets for LDS-hist binning
#define CAPB 2048    // fixed payload slots per bucket (mean ~1279 here)

typedef short bf16x8 __attribute__((ext_vector_type(8)));
typedef float f32x4  __attribute__((ext_vector_type(4)));

__device__ __forceinline__ unsigned short f2bf(float f) {
    unsigned u = __builtin_bit_cast(unsigned, f);
    unsigned r = (u + 0x7fffu + ((u >> 16) & 1u)) >> 16;   // round-nearest-even
    return (unsigned short)r;
}
__device__ __forceinline__ float bf2f(unsigned short h) {
    return __builtin_bit_cast(float, (unsigned)h << 16);
}
__device__ __forceinline__ unsigned pack2(float a, float b) {
    return (unsigned)f2bf(a) | ((unsigned)f2bf(b) << 16);
}

// ---------------------------------------------------------------------------
// Prep: W (4x64x64 f32) + root_w -> bf16, transposed [m][col][k], XOR-swizzled
// ( byte ^= (col&7)<<4 within each 128B row ) — the exact LDS image gemm wants.
// ALSO zeros cursor[0..nb] (cursor[nb] doubles as spill_cnt) — replaces the
// hipMemsetAsync dispatch, which cost ~43 us per replay.
// ---------------------------------------------------------------------------
__global__ __launch_bounds__(256) void prep_w_kernel(
    const float* __restrict__ weight, const float* __restrict__ root_w,
    unsigned short* __restrict__ wt, int* __restrict__ cursor, int nb)
{
    int g = blockIdx.x * 256 + threadIdx.x;
    if (g <= nb) cursor[g] = 0;
    if (g >= 5 * 4096) return;
    int m = g >> 12, rem = g & 4095, c = rem >> 6, k = rem & 63;
    float v = (m < 4) ? weight[m * 4096 + k * 64 + c] : root_w[k * 64 + c];
    int byte = m * 8192 + c * 128 + ((k * 2) ^ ((c & 7) << 4));
    wt[byte >> 1] = f2bf(v);
}

// ---------------------------------------------------------------------------
// MFMA GEMM: 64-node tile, all 5 products per block, one barrier.
//   m in [0,3] -> y[m] = x @ weight[m]   (bf16)
//   m == 4     -> out  = x @ root_w + b  (f32, initializes out)
// LDS image: [0,8KB): x tile row-major bf16 swizzled; [8KB,48KB): Wt (5 mats).
// Wave wv owns nodes wv*16..+15; 4 col-tiles of 16; K=64 as 2 MFMA k-steps.
// ---------------------------------------------------------------------------
__global__ __launch_bounds__(256) void gemm_mfma_kernel(
    const float* __restrict__ x, const uint4* __restrict__ wt4,
    const float* __restrict__ root_b,
    float* __restrict__ out, unsigned short* __restrict__ y, int n_nodes)
{
    __shared__ uint4 lds4[3072];   // 48 KB

    const int tid   = threadIdx.x;
    const int node0 = blockIdx.x * 64;

    // Stage all 5 Wt (pre-swizzled in global -> linear copy).
    for (int i = tid; i < 2560; i += 256) lds4[512 + i] = wt4[i];

    // Stage x tile: thread -> node n = tid>>2, k-chunk kq = tid&3 (16 elems).
    {
        int n    = tid >> 2;
        int kq   = tid & 3;
        int node = node0 + n;
        uint4 p0, p1;
        if (node < n_nodes) {
            const float4* src = reinterpret_cast<const float4*>(x)
                                + (size_t)node * 16 + kq * 4;
            float4 f0 = src[0], f1 = src[1], f2 = src[2], f3 = src[3];
            p0.x = pack2(f0.x, f0.y); p0.y = pack2(f0.z, f0.w);
            p0.z = pack2(f1.x, f1.y); p0.w = pack2(f1.z, f1.w);
            p1.x = pack2(f2.x, f2.y); p1.y = pack2(f2.z, f2.w);
            p1.z = pack2(f3.x, f3.y); p1.w = pack2(f3.z, f3.w);
        } else {
            p0 = make_uint4(0, 0, 0, 0);
            p1 = p0;
        }
        int s0 = (kq * 2) ^ (n & 7);
        lds4[n * 8 + s0]       = p0;
        lds4[n * 8 + (s0 ^ 1)] = p1;
    }
    __syncthreads();

    const int wv = tid >> 6;
    const int l  = tid & 63;
    const int lo = l & 15;
    const int hi = l >> 4;

    // A fragments (m-invariant): row = wv*16+lo, k = ks*32 + hi*8 .. +7
    const int arow = wv * 16 + lo;
    bf16x8 a0 = *reinterpret_cast<const bf16x8*>(
        &lds4[arow * 8 + ((0 + hi) ^ (arow & 7))]);
    bf16x8 a1 = *reinterpret_cast<const bf16x8*>(
        &lds4[arow * 8 + ((4 + hi) ^ (arow & 7))]);

    for (int m = 0; m < 5; ++m) {
        f32x4 acc[4];
        #pragma unroll
        for (int ct = 0; ct < 4; ++ct)
            acc[ct] = (f32x4){0.f, 0.f, 0.f, 0.f};

        #pragma unroll
        for (int ct = 0; ct < 4; ++ct) {
            int c     = ct * 16 + lo;
            int bbase = 512 + m * 512 + c * 8;
            bf16x8 b0 = *reinterpret_cast<const bf16x8*>(
                &lds4[bbase + ((0 + hi) ^ (c & 7))]);
            acc[ct] = __builtin_amdgcn_mfma_f32_16x16x32_bf16(a0, b0, acc[ct], 0, 0, 0);
            bf16x8 b1 = *reinterpret_cast<const bf16x8*>(
                &lds4[bbase + ((4 + hi) ^ (c & 7))]);
            acc[ct] = __builtin_amdgcn_mfma_f32_16x16x32_bf16(a1, b1, acc[ct], 0, 0, 0);
        }

        if (m < 4) {
            unsigned short* __restrict__ ym = y + (size_t)m * n_nodes * 64;
            #pragma unroll
            for (int ct = 0; ct < 4; ++ct) {
                int col = ct * 16 + lo;
                #pragma unroll
                for (int r = 0; r < 4; ++r) {
                    int node = node0 + wv * 16 + hi * 4 + r;
                    if (node < n_nodes)
                        ym[(size_t)node * 64 + col] = f2bf(acc[ct][r]);
                }
            }
        } else {
            #pragma unroll
            for (int ct = 0; ct < 4; ++ct) {
                int col = ct * 16 + lo;
                float rb = root_b[col];
                #pragma unroll
                for (int r = 0; r < 4; ++r) {
                    int node = node0 + wv * 16 + hi * 4 + r;
                    if (node < n_nodes)
                        out[(size_t)node * 64 + col] = acc[ct][r] + rb;
                }
            }
        }
    }
}

// ---------------------------------------------------------------------------
// Fill: bin edges into FIXED-capacity bucket slots (payload[b*CAPB + pos]).
// payload = src | (dst&63)<<ssh | type<<tsh.  spill_cnt = &cursor[nb].
// ---------------------------------------------------------------------------
__global__ __launch_bounds__(256) void fillb_kernel(
    const int* __restrict__ ei, const int* __restrict__ et,
    int* __restrict__ cursor, int* __restrict__ spill,
    unsigned* __restrict__ payload,
    int n_edges, int nb, int ssh, int tsh)
{
    __shared__ int lh[NBMAX];
    __shared__ int lbase[NBMAX];
    const int chunk = (n_edges + gridDim.x - 1) / gridDim.x;
    const int lo = blockIdx.x * chunk;
    const int hi = min(lo + chunk, n_edges);
    for (int i = threadIdx.x; i < nb; i += 256) lh[i] = 0;
    __syncthreads();
    for (int e = lo + threadIdx.x; e < hi; e += 256)
        atomicAdd(&lh[ei[n_edges + e] >> 6], 1);
    __syncthreads();
    for (int i = threadIdx.x; i < nb; i += 256) {
        int c = lh[i];
        lbase[i] = c ? atomicAdd(&cursor[i], c) : 0;
        lh[i] = 0;
    }
    __syncthreads();
    for (int e = lo + threadIdx.x; e < hi; e += 256) {
        int src = ei[e];
        int d   = ei[n_edges + e];
        int t   = et[e];
        int b   = d >> 6;
        int r   = atomicAdd(&lh[b], 1);
        int pos = lbase[b] + r;
        if (pos < CAPB) {
            payload[(size_t)b * CAPB + pos] =
                (unsigned)src | ((unsigned)(d & 63) << ssh) | ((unsigned)t << tsh);
        } else {
            int sp = atomicAdd(&cursor[nb], 1);
            spill[sp] = e;
        }
    }
}

// ---------------------------------------------------------------------------
// Gather (bf16 y): one 1024-thread block per bucket; in-LDS counting sort by
// local dst, then 64 groups x 16 threads accumulate in registers. No atomics.
// ---------------------------------------------------------------------------
__global__ __launch_bounds__(1024) void gatherb2_kernel(
    const int* __restrict__ cursor, const unsigned* __restrict__ payload,
    const unsigned short* __restrict__ y, float* __restrict__ out,
    int n_nodes, int ssh, int tsh)
{
    __shared__ unsigned raw[CAPB];
    __shared__ unsigned srt[CAPB];
    __shared__ int hist[64];
    __shared__ int hoff[65];

    const int tid = threadIdx.x;
    const int b   = blockIdx.x;
    const int n_in = min(cursor[b], CAPB);
    const unsigned* __restrict__ pl_base = payload + (size_t)b * CAPB;

    if (tid < 64) hist[tid] = 0;
    __syncthreads();
    for (int i = tid; i < n_in; i += 1024) {
        unsigned pl = pl_base[i];
        raw[i] = pl;
        atomicAdd(&hist[(pl >> ssh) & 63], 1);
    }
    __syncthreads();
    if (tid < 64) {                       // wave-parallel exclusive scan
        int v = hist[tid];
        int s = v;
        #pragma unroll
        for (int d = 1; d < 64; d <<= 1) {
            int u = __shfl_up(s, d, 64);
            if (tid >= d) s += u;
        }
        hoff[tid] = s - v;
        if (tid == 63) hoff[64] = s;
        hist[tid] = 0;
    }
    __syncthreads();
    for (int i = tid; i < n_in; i += 1024) {
        unsigned pl = raw[i];
        int lnode = (pl >> ssh) & 63;
        int r = atomicAdd(&hist[lnode], 1);
        srt[hoff[lnode] + r] = pl;
    }
    __syncthreads();

    const int g    = tid >> 4;
    const int cq   = tid & 15;
    const int node = b * 64 + g;
    const unsigned smask = (1u << ssh) - 1;

    float4 acc = make_float4(0.f, 0.f, 0.f, 0.f);
    const int s0 = hoff[g];
    const int s1 = hoff[g + 1];
    for (int p = s0; p < s1; ++p) {
        unsigned pl = srt[p];
        int src = (int)(pl & smask);
        int t   = (int)(pl >> tsh);
        ushort4 v = reinterpret_cast<const ushort4*>(y)[((long)t * n_nodes + src) * 16 + cq];
        acc.x += bf2f(v.x); acc.y += bf2f(v.y);
        acc.z += bf2f(v.z); acc.w += bf2f(v.w);
    }
    if (node < n_nodes) {
        float4* o  = reinterpret_cast<float4*>(out) + (long)node * 16 + cq;
        float4 cur = *o;
        cur.x += acc.x; cur.y += acc.y; cur.z += acc.z; cur.w += acc.w;
        *o = cur;
    }
}

// Drain overflow spill list (normally empty). spill_cnt = &cursor[nb].
__global__ __launch_bounds__(256) void spill_kernel(
    const int* __restrict__ ei, const int* __restrict__ et,
    const int* __restrict__ cursor, int nb, const int* __restrict__ spill,
    const unsigned short* __restrict__ y, float* __restrict__ out,
    int n_edges, int n_nodes)
{
    const int n = cursor[nb];
    const long total  = (long)n * 16;
    const long stride = (long)gridDim.x * 256;
    for (long i = blockIdx.x * 256 + threadIdx.x; i < total; i += stride) {
        int e  = spill[i >> 4];
        int cq = (int)(i & 15);
        int src  = ei[e];
        int dstn = ei[n_edges + e];
        int t    = et[e];
        ushort4 v = reinterpret_cast<const ushort4*>(y)[((long)t * n_nodes + src) * 16 + cq];
        float* o = out + (long)dstn * 64 + cq * 4;
        atomicAdd(o + 0, bf2f(v.x));
        atomicAdd(o + 1, bf2f(v.y));
        atomicAdd(o + 2, bf2f(v.z));
        atomicAdd(o + 3, bf2f(v.w));
    }
}

// --------------------- fallbacks (small workspace) -------------------------
__global__ __launch_bounds__(256) void gemm_fused2_kernel(
    const float* __restrict__ x, const float* __restrict__ weight,
    const float* __restrict__ root_w, const float* __restrict__ root_b,
    float* __restrict__ out, unsigned short* __restrict__ y, int n_nodes)
{
    __shared__ unsigned short xsT[64][72];
    __shared__ float ws[64][72];
    const int tid   = threadIdx.x;
    const int node0 = blockIdx.x * 64;
    #pragma unroll
    for (int i = 0; i < 4; ++i) {
        int v    = tid + i * 256;
        int r    = v >> 4;
        int cq   = v & 15;
        int node = node0 + r;
        float4 x4 = (node < n_nodes)
                        ? reinterpret_cast<const float4*>(x)[(size_t)node * 16 + cq]
                        : make_float4(0.f, 0.f, 0.f, 0.f);
        xsT[cq * 4 + 0][r] = f2bf(x4.x);
        xsT[cq * 4 + 1][r] = f2bf(x4.y);
        xsT[cq * 4 + 2][r] = f2bf(x4.z);
        xsT[cq * 4 + 3][r] = f2bf(x4.w);
    }
    const int ng = tid & 31;
    const int cg = tid >> 5;
    float bias[8];
    #pragma unroll
    for (int j = 0; j < 8; ++j) bias[j] = root_b[cg * 8 + j];
    for (int m = 0; m < 5; ++m) {
        const float* __restrict__ W = (m < 4) ? (weight + m * 4096) : root_w;
        __syncthreads();
        #pragma unroll
        for (int i = 0; i < 4; ++i) {
            int v  = tid + i * 256;
            int r  = v >> 4;
            int cq = v & 15;
            float4 w4 = reinterpret_cast<const float4*>(W)[v];
            ws[r][cq * 4 + 0] = w4.x; ws[r][cq * 4 + 1] = w4.y;
            ws[r][cq * 4 + 2] = w4.z; ws[r][cq * 4 + 3] = w4.w;
        }
        __syncthreads();
        float acc[2][8];
        #pragma unroll
        for (int i = 0; i < 2; ++i)
            #pragma unroll
            for (int j = 0; j < 8; ++j) acc[i][j] = 0.f;
        #pragma unroll 4
        for (int k = 0; k < 64; ++k) {
            unsigned xu = *reinterpret_cast<const unsigned*>(&xsT[k][ng * 2]);
            float xv0 = __builtin_bit_cast(float, xu << 16);
            float xv1 = __builtin_bit_cast(float, xu & 0xffff0000u);
            float4 wa = *reinterpret_cast<const float4*>(&ws[k][cg * 8]);
            float4 wb = *reinterpret_cast<const float4*>(&ws[k][cg * 8 + 4]);
            float wv[8] = {wa.x, wa.y, wa.z, wa.w, wb.x, wb.y, wb.z, wb.w};
            #pragma unroll
            for (int j = 0; j < 8; ++j) {
                acc[0][j] += xv0 * wv[j];
                acc[1][j] += xv1 * wv[j];
            }
        }
        #pragma unroll
        for (int i = 0; i < 2; ++i) {
            int node = node0 + ng * 2 + i;
            if (node >= n_nodes) continue;
            if (m < 4) {
                uint4 o;
                o.x = pack2(acc[i][0], acc[i][1]);
                o.y = pack2(acc[i][2], acc[i][3]);
                o.z = pack2(acc[i][4], acc[i][5]);
                o.w = pack2(acc[i][6], acc[i][7]);
                *reinterpret_cast<uint4*>(
                    &y[((size_t)m * n_nodes + node) * 64 + cg * 8]) = o;
            } else {
                float4 oa = make_float4(acc[i][0] + bias[0], acc[i][1] + bias[1],
                                        acc[i][2] + bias[2], acc[i][3] + bias[3]);
                float4 ob = make_float4(acc[i][4] + bias[4], acc[i][5] + bias[5],
                                        acc[i][6] + bias[6], acc[i][7] + bias[7]);
                reinterpret_cast<float4*>(&out[(size_t)node * 64 + cg * 8])[0] = oa;
                reinterpret_cast<float4*>(&out[(size_t)node * 64 + cg * 8])[1] = ob;
            }
        }
    }
}

__global__ __launch_bounds__(256) void scatter_kernel(
    const int* __restrict__ ei, const int* __restrict__ et,
    const unsigned short* __restrict__ y, float* __restrict__ out,
    int n_edges, int n_nodes)
{
    long idx = (long)blockIdx.x * blockDim.x + threadIdx.x;
    if (idx >= (long)n_edges * 16) return;
    int e  = (int)(idx >> 4);
    int cq = (int)(idx & 15);
    int src  = ei[e];
    int dstn = ei[n_edges + e];
    int t    = et[e];
    ushort4 v = reinterpret_cast<const ushort4*>(y)[((long)t * n_nodes + src) * 16 + cq];
    float* o = out + (long)dstn * 64 + cq * 4;
    atomicAdd(o + 0, bf2f(v.x));
    atomicAdd(o + 1, bf2f(v.y));
    atomicAdd(o + 2, bf2f(v.z));
    atomicAdd(o + 3, bf2f(v.w));
}

__global__ __launch_bounds__(256) void gemm_root_kernel(
    const float* __restrict__ x, const float* __restrict__ root_w,
    const float* __restrict__ root_b, float* __restrict__ out, int n_nodes)
{
    __shared__ float xs[NT][65];
    __shared__ float ws[64][65];
    const int tid   = threadIdx.x;
    const int node0 = blockIdx.x * NT;
    #pragma unroll
    for (int i = 0; i < 4; ++i) {
        int v  = tid + i * 256;
        int r  = v >> 4;
        int cq = v & 15;
        float4 w4 = reinterpret_cast<const float4*>(root_w)[v];
        ws[r][cq * 4 + 0] = w4.x; ws[r][cq * 4 + 1] = w4.y;
        ws[r][cq * 4 + 2] = w4.z; ws[r][cq * 4 + 3] = w4.w;
        int node = node0 + r;
        float4 x4 = (node < n_nodes)
                        ? reinterpret_cast<const float4*>(x)[node * 16 + cq]
                        : make_float4(0.f, 0.f, 0.f, 0.f);
        xs[r][cq * 4 + 0] = x4.x; xs[r][cq * 4 + 1] = x4.y;
        xs[r][cq * 4 + 2] = x4.z; xs[r][cq * 4 + 3] = x4.w;
    }
    __syncthreads();
    const int tc = (tid & 15) * 4;
    const int tr = (tid >> 4) * 4;
    float acc[4][4];
    #pragma unroll
    for (int i = 0; i < 4; ++i)
        #pragma unroll
        for (int j = 0; j < 4; ++j) acc[i][j] = 0.f;
    #pragma unroll 4
    for (int k = 0; k < 64; ++k) {
        float xv[4], wv[4];
        #pragma unroll
        for (int i = 0; i < 4; ++i) xv[i] = xs[tr + i][k];
        #pragma unroll
        for (int j = 0; j < 4; ++j) wv[j] = ws[k][tc + j];
        #pragma unroll
        for (int i = 0; i < 4; ++i)
            #pragma unroll
            for (int j = 0; j < 4; ++j) acc[i][j] += xv[i] * wv[j];
    }
    #pragma unroll
    for (int i = 0; i < 4; ++i) {
        int node = node0 + tr + i;
        if (node < n_nodes) {
            float4 o = make_float4(acc[i][0] + root_b[tc + 0], acc[i][1] + root_b[tc + 1],
                                   acc[i][2] + root_b[tc + 2], acc[i][3] + root_b[tc + 3]);
            reinterpret_cast<float4*>(out)[node * 16 + (tc >> 2)] = o;
        }
    }
}

__global__ __launch_bounds__(256) void edge_direct_kernel(
    const float* __restrict__ x, const int* __restrict__ ei,
    const int* __restrict__ et, const float* __restrict__ weight,
    float* __restrict__ out, int n_edges)
{
    int gwave  = (int)((blockIdx.x * (long)blockDim.x + threadIdx.x) >> 6);
    int lane   = threadIdx.x & 63;
    int nwaves = (int)(((long)gridDim.x * blockDim.x) >> 6);
    for (int e = gwave; e < n_edges; e += nwaves) {
        int src  = ei[e];
        int dstn = ei[n_edges + e];
        int t    = et[e];
        float xv = x[src * 64 + lane];
        const float* __restrict__ W = weight + t * 4096;
        float acc = 0.f;
        #pragma unroll 8
        for (int k = 0; k < 64; ++k) {
            float xk = __shfl(xv, k);
            acc += xk * W[k * 64 + lane];
        }
        atomicAdd(&out[(long)dstn * 64 + lane], acc);
    }
}

extern "C" void kernel_launch(void* const* d_in, const int* in_sizes, int n_in,
                              void* d_out, int out_size, void* d_ws, size_t ws_size,
                              hipStream_t stream) {
    const float* x      = (const float*)d_in[0];
    const int*   ei     = (const int*)d_in[1];   // [2, E] int32
    const int*   et     = (const int*)d_in[2];   // [E]
    const float* weight = (const float*)d_in[3]; // [4, 64, 64]
    const float* root_w = (const float*)d_in[4]; // [64, 64]
    const float* root_b = (const float*)d_in[5]; // [64]
    float* out = (float*)d_out;

    const int n_nodes = in_sizes[0] / 64;
    const int n_edges = in_sizes[2];
    const int nb      = (n_nodes + 63) >> 6;

    int ssh = 1;
    while ((1 << ssh) < n_nodes) ++ssh;   // bits for src
    const int tsh = ssh + 6;              // 6 bits for local dst

    const size_t wt_bytes = 5 * 4096 * sizeof(unsigned short);   // 40 KB
    const size_t y_bytes  = (size_t)4 * n_nodes * 64 * sizeof(unsigned short);
    const size_t b_bytes  = wt_bytes + y_bytes +
        ((size_t)nb + 1 + (size_t)nb * CAPB + n_edges) * 4;

    if (nb <= NBMAX && tsh + 2 <= 32 && ws_size >= b_bytes) {
        unsigned short* wt      = (unsigned short*)d_ws;
        unsigned short* y       = (unsigned short*)((char*)d_ws + wt_bytes);
        int*            cursor  = (int*)((char*)d_ws + wt_bytes + y_bytes); // nb+1 (last = spill_cnt)
        unsigned*       payload = (unsigned*)(cursor + nb + 1);             // nb*CAPB
        int*            spill   = (int*)(payload + (size_t)nb * CAPB);      // n_edges

        prep_w_kernel<<<80, 256, 0, stream>>>(weight, root_w, wt, cursor, nb);
        fillb_kernel<<<256, 256, 0, stream>>>(ei, et, cursor, spill,
                                              payload, n_edges, nb, ssh, tsh);
        gemm_mfma_kernel<<<nb, 256, 0, stream>>>(x, (const uint4*)wt, root_b,
                                                 out, y, n_nodes);
        gatherb2_kernel<<<nb, 1024, 0, stream>>>(cursor, payload, y, out,
                                                 n_nodes, ssh, tsh);
        spill_kernel<<<64, 256, 0, stream>>>(ei, et, cursor, nb, spill, y, out,
                                             n_edges, n_nodes);
    } else if (ws_size >= y_bytes) {
        unsigned short* y = (unsigned short*)d_ws;
        gemm_fused2_kernel<<<(n_nodes + 63) / 64, 256, 0, stream>>>(
            x, weight, root_w, root_b, out, y, n_nodes);
        long total  = (long)n_edges * 16;
        int  blocks = (int)((total + 255) / 256);
        scatter_kernel<<<blocks, 256, 0, stream>>>(ei, et, y, out, n_edges, n_nodes);
    } else {
        gemm_root_kernel<<<(n_nodes + NT - 1) / NT, 256, 0, stream>>>(
            x, root_w, root_b, out, n_nodes);
        edge_direct_kernel<<<4096, 256, 0, stream>>>(x, ei, et, weight, out, n_edges);
    }
}

// Round 10
// 66.993 us; speedup vs baseline: 7.7110x; 1.2672x over previous
//
#include <hip/hip_runtime.h>

#define NT 64
#define NBMAX 4096   // max 64-node buckets for LDS-hist binning
#define CAPB 2048    // fixed payload slots per bucket (mean ~1279 here)
#define FILLB 256    // blocks devoted to fill inside the fused kernel

typedef short bf16x8 __attribute__((ext_vector_type(8)));
typedef float f32x4  __attribute__((ext_vector_type(4)));

__device__ __forceinline__ unsigned short f2bf(float f) {
    unsigned u = __builtin_bit_cast(unsigned, f);
    unsigned r = (u + 0x7fffu + ((u >> 16) & 1u)) >> 16;   // round-nearest-even
    return (unsigned short)r;
}
__device__ __forceinline__ float bf2f(unsigned short h) {
    return __builtin_bit_cast(float, (unsigned)h << 16);
}
__device__ __forceinline__ unsigned pack2(float a, float b) {
    return (unsigned)f2bf(a) | ((unsigned)f2bf(b) << 16);
}

// ---------------------------------------------------------------------------
// Prep: W (4x64x64 f32) + root_w -> bf16, transposed [m][col][k], XOR-swizzled
// (byte ^= (col&7)<<4 within each 128B row) — the exact LDS image gemm wants.
// ALSO zeros cursor[0..nb] (cursor[nb] doubles as spill_cnt).
// ---------------------------------------------------------------------------
__global__ __launch_bounds__(256) void prep_w_kernel(
    const float* __restrict__ weight, const float* __restrict__ root_w,
    unsigned short* __restrict__ wt, int* __restrict__ cursor, int nb)
{
    int g = blockIdx.x * 256 + threadIdx.x;
    if (g <= nb) cursor[g] = 0;
    if (g >= 5 * 4096) return;
    int m = g >> 12, rem = g & 4095, c = rem >> 6, k = rem & 63;
    float v = (m < 4) ? weight[m * 4096 + k * 64 + c] : root_w[k * 64 + c];
    int byte = m * 8192 + c * 128 + ((k * 2) ^ ((c & 7) << 4));
    wt[byte >> 1] = f2bf(v);
}

// ---------------------------------------------------------------------------
// Fused fill ∥ gemm: blocks [0,FILLB) bin edges; blocks [FILLB, FILLB+nb)
// run the MFMA GEMM. The two jobs are data-independent and overlap on-chip.
// ---------------------------------------------------------------------------
__global__ __launch_bounds__(256) void fused_fg_kernel(
    // gemm args
    const float* __restrict__ x, const uint4* __restrict__ wt4,
    const float* __restrict__ root_b,
    float* __restrict__ out, unsigned short* __restrict__ y, int n_nodes,
    // fill args
    const int* __restrict__ ei, const int* __restrict__ et,
    int* __restrict__ cursor, int* __restrict__ spill,
    unsigned* __restrict__ payload, int n_edges, int nb, int ssh, int tsh)
{
    __shared__ __align__(16) char smem[49152];   // 48 KB, shared by both paths
    const int tid = threadIdx.x;

    if (blockIdx.x < FILLB) {
        // ------------------------- FILL path -------------------------------
        int* lh    = (int*)smem;          // NBMAX
        int* lbase = lh + NBMAX;          // NBMAX
        const int chunk = (n_edges + FILLB - 1) / FILLB;
        const int lo = blockIdx.x * chunk;
        const int hi = min(lo + chunk, n_edges);
        for (int i = tid; i < nb; i += 256) lh[i] = 0;
        __syncthreads();
        for (int e = lo + tid; e < hi; e += 256)
            atomicAdd(&lh[ei[n_edges + e] >> 6], 1);
        __syncthreads();
        for (int i = tid; i < nb; i += 256) {
            int c = lh[i];
            lbase[i] = c ? atomicAdd(&cursor[i], c) : 0;
            lh[i] = 0;
        }
        __syncthreads();
        for (int e = lo + tid; e < hi; e += 256) {
            int src = ei[e];
            int d   = ei[n_edges + e];
            int t   = et[e];
            int b   = d >> 6;
            int r   = atomicAdd(&lh[b], 1);
            int pos = lbase[b] + r;
            if (pos < CAPB) {
                payload[(size_t)b * CAPB + pos] =
                    (unsigned)src | ((unsigned)(d & 63) << ssh) | ((unsigned)t << tsh);
            } else {
                int sp = atomicAdd(&cursor[nb], 1);
                spill[sp] = e;
            }
        }
        return;
    }

    // --------------------------- GEMM path ---------------------------------
    uint4* lds4 = (uint4*)smem;          // 3072 entries
    const int node0 = (blockIdx.x - FILLB) * 64;

    for (int i = tid; i < 2560; i += 256) lds4[512 + i] = wt4[i];

    {
        int n    = tid >> 2;
        int kq   = tid & 3;
        int node = node0 + n;
        uint4 p0, p1;
        if (node < n_nodes) {
            const float4* src = reinterpret_cast<const float4*>(x)
                                + (size_t)node * 16 + kq * 4;
            float4 f0 = src[0], f1 = src[1], f2 = src[2], f3 = src[3];
            p0.x = pack2(f0.x, f0.y); p0.y = pack2(f0.z, f0.w);
            p0.z = pack2(f1.x, f1.y); p0.w = pack2(f1.z, f1.w);
            p1.x = pack2(f2.x, f2.y); p1.y = pack2(f2.z, f2.w);
            p1.z = pack2(f3.x, f3.y); p1.w = pack2(f3.z, f3.w);
        } else {
            p0 = make_uint4(0, 0, 0, 0);
            p1 = p0;
        }
        int s0 = (kq * 2) ^ (n & 7);
        lds4[n * 8 + s0]       = p0;
        lds4[n * 8 + (s0 ^ 1)] = p1;
    }
    __syncthreads();

    const int wv = tid >> 6;
    const int l  = tid & 63;
    const int lo = l & 15;
    const int hi = l >> 4;

    const int arow = wv * 16 + lo;
    bf16x8 a0 = *reinterpret_cast<const bf16x8*>(
        &lds4[arow * 8 + ((0 + hi) ^ (arow & 7))]);
    bf16x8 a1 = *reinterpret_cast<const bf16x8*>(
        &lds4[arow * 8 + ((4 + hi) ^ (arow & 7))]);

    for (int m = 0; m < 5; ++m) {
        f32x4 acc[4];
        #pragma unroll
        for (int ct = 0; ct < 4; ++ct)
            acc[ct] = (f32x4){0.f, 0.f, 0.f, 0.f};

        #pragma unroll
        for (int ct = 0; ct < 4; ++ct) {
            int c     = ct * 16 + lo;
            int bbase = 512 + m * 512 + c * 8;
            bf16x8 b0 = *reinterpret_cast<const bf16x8*>(
                &lds4[bbase + ((0 + hi) ^ (c & 7))]);
            acc[ct] = __builtin_amdgcn_mfma_f32_16x16x32_bf16(a0, b0, acc[ct], 0, 0, 0);
            bf16x8 b1 = *reinterpret_cast<const bf16x8*>(
                &lds4[bbase + ((4 + hi) ^ (c & 7))]);
            acc[ct] = __builtin_amdgcn_mfma_f32_16x16x32_bf16(a1, b1, acc[ct], 0, 0, 0);
        }

        if (m < 4) {
            unsigned short* __restrict__ ym = y + (size_t)m * n_nodes * 64;
            #pragma unroll
            for (int ct = 0; ct < 4; ++ct) {
                int col = ct * 16 + lo;
                #pragma unroll
                for (int r = 0; r < 4; ++r) {
                    int node = node0 + wv * 16 + hi * 4 + r;
                    if (node < n_nodes)
                        ym[(size_t)node * 64 + col] = f2bf(acc[ct][r]);
                }
            }
        } else {
            #pragma unroll
            for (int ct = 0; ct < 4; ++ct) {
                int col = ct * 16 + lo;
                float rb = root_b[col];
                #pragma unroll
                for (int r = 0; r < 4; ++r) {
                    int node = node0 + wv * 16 + hi * 4 + r;
                    if (node < n_nodes)
                        out[(size_t)node * 64 + col] = acc[ct][r] + rb;
                }
            }
        }
    }
}

// ---------------------------------------------------------------------------
// Gather (bf16 y): one 1024-thread block per bucket; in-LDS counting sort by
// local dst, then 64 groups x 16 threads accumulate in registers (unroll x2).
// Also drains the (normally empty) spill list for its own bucket.
// ---------------------------------------------------------------------------
__global__ __launch_bounds__(1024) void gatherb3_kernel(
    const int* __restrict__ cursor, const unsigned* __restrict__ payload,
    const int* __restrict__ spill, const int* __restrict__ ei,
    const int* __restrict__ et,
    const unsigned short* __restrict__ y, float* __restrict__ out,
    int n_nodes, int n_edges, int nb, int ssh, int tsh)
{
    __shared__ unsigned raw[CAPB];
    __shared__ unsigned srt[CAPB];
    __shared__ int hist[64];
    __shared__ int hoff[65];

    const int tid = threadIdx.x;
    const int b   = blockIdx.x;
    const int n_in = min(cursor[b], CAPB);
    const unsigned* __restrict__ pl_base = payload + (size_t)b * CAPB;

    if (tid < 64) hist[tid] = 0;
    __syncthreads();
    for (int i = tid; i < n_in; i += 1024) {
        unsigned pl = pl_base[i];
        raw[i] = pl;
        atomicAdd(&hist[(pl >> ssh) & 63], 1);
    }
    __syncthreads();
    if (tid < 64) {                       // wave-parallel exclusive scan
        int v = hist[tid];
        int s = v;
        #pragma unroll
        for (int d = 1; d < 64; d <<= 1) {
            int u = __shfl_up(s, d, 64);
            if (tid >= d) s += u;
        }
        hoff[tid] = s - v;
        if (tid == 63) hoff[64] = s;
        hist[tid] = 0;
    }
    __syncthreads();
    for (int i = tid; i < n_in; i += 1024) {
        unsigned pl = raw[i];
        int lnode = (pl >> ssh) & 63;
        int r = atomicAdd(&hist[lnode], 1);
        srt[hoff[lnode] + r] = pl;
    }
    __syncthreads();

    const int g    = tid >> 4;
    const int cq   = tid & 15;
    const int node = b * 64 + g;
    const unsigned smask = (1u << ssh) - 1;
    const ushort4* __restrict__ y4 = reinterpret_cast<const ushort4*>(y);

    float4 acc = make_float4(0.f, 0.f, 0.f, 0.f);
    const int s0 = hoff[g];
    const int s1 = hoff[g + 1];
    int p = s0;
    for (; p + 1 < s1; p += 2) {          // unroll x2: paired independent loads
        unsigned pl0 = srt[p];
        unsigned pl1 = srt[p + 1];
        ushort4 v0 = y4[((long)(pl0 >> tsh) * n_nodes + (pl0 & smask)) * 16 + cq];
        ushort4 v1 = y4[((long)(pl1 >> tsh) * n_nodes + (pl1 & smask)) * 16 + cq];
        acc.x += bf2f(v0.x) + bf2f(v1.x);
        acc.y += bf2f(v0.y) + bf2f(v1.y);
        acc.z += bf2f(v0.z) + bf2f(v1.z);
        acc.w += bf2f(v0.w) + bf2f(v1.w);
    }
    if (p < s1) {
        unsigned pl = srt[p];
        ushort4 v = y4[((long)(pl >> tsh) * n_nodes + (pl & smask)) * 16 + cq];
        acc.x += bf2f(v.x); acc.y += bf2f(v.y);
        acc.z += bf2f(v.z); acc.w += bf2f(v.w);
    }

    // Spill drain (normally S == 0).
    const int S = cursor[nb];
    for (int i = 0; i < S; ++i) {
        int e = spill[i];
        int d = ei[n_edges + e];
        if ((d >> 6) == b && (d & 63) == g) {
            int src = ei[e];
            int t   = et[e];
            ushort4 v = y4[((long)t * n_nodes + src) * 16 + cq];
            acc.x += bf2f(v.x); acc.y += bf2f(v.y);
            acc.z += bf2f(v.z); acc.w += bf2f(v.w);
        }
    }

    if (node < n_nodes) {
        float4* o  = reinterpret_cast<float4*>(out) + (long)node * 16 + cq;
        float4 cur = *o;
        cur.x += acc.x; cur.y += acc.y; cur.z += acc.z; cur.w += acc.w;
        *o = cur;
    }
}

// --------------------- fallbacks (small workspace) -------------------------
__global__ __launch_bounds__(256) void gemm_fused2_kernel(
    const float* __restrict__ x, const float* __restrict__ weight,
    const float* __restrict__ root_w, const float* __restrict__ root_b,
    float* __restrict__ out, unsigned short* __restrict__ y, int n_nodes)
{
    __shared__ unsigned short xsT[64][72];
    __shared__ float ws[64][72];
    const int tid   = threadIdx.x;
    const int node0 = blockIdx.x * 64;
    #pragma unroll
    for (int i = 0; i < 4; ++i) {
        int v    = tid + i * 256;
        int r    = v >> 4;
        int cq   = v & 15;
        int node = node0 + r;
        float4 x4 = (node < n_nodes)
                        ? reinterpret_cast<const float4*>(x)[(size_t)node * 16 + cq]
                        : make_float4(0.f, 0.f, 0.f, 0.f);
        xsT[cq * 4 + 0][r] = f2bf(x4.x);
        xsT[cq * 4 + 1][r] = f2bf(x4.y);
        xsT[cq * 4 + 2][r] = f2bf(x4.z);
        xsT[cq * 4 + 3][r] = f2bf(x4.w);
    }
    const int ng = tid & 31;
    const int cg = tid >> 5;
    float bias[8];
    #pragma unroll
    for (int j = 0; j < 8; ++j) bias[j] = root_b[cg * 8 + j];
    for (int m = 0; m < 5; ++m) {
        const float* __restrict__ W = (m < 4) ? (weight + m * 4096) : root_w;
        __syncthreads();
        #pragma unroll
        for (int i = 0; i < 4; ++i) {
            int v  = tid + i * 256;
            int r  = v >> 4;
            int cq = v & 15;
            float4 w4 = reinterpret_cast<const float4*>(W)[v];
            ws[r][cq * 4 + 0] = w4.x; ws[r][cq * 4 + 1] = w4.y;
            ws[r][cq * 4 + 2] = w4.z; ws[r][cq * 4 + 3] = w4.w;
        }
        __syncthreads();
        float acc[2][8];
        #pragma unroll
        for (int i = 0; i < 2; ++i)
            #pragma unroll
            for (int j = 0; j < 8; ++j) acc[i][j] = 0.f;
        #pragma unroll 4
        for (int k = 0; k < 64; ++k) {
            unsigned xu = *reinterpret_cast<const unsigned*>(&xsT[k][ng * 2]);
            float xv0 = __builtin_bit_cast(float, xu << 16);
            float xv1 = __builtin_bit_cast(float, xu & 0xffff0000u);
            float4 wa = *reinterpret_cast<const float4*>(&ws[k][cg * 8]);
            float4 wb = *reinterpret_cast<const float4*>(&ws[k][cg * 8 + 4]);
            float wv[8] = {wa.x, wa.y, wa.z, wa.w, wb.x, wb.y, wb.z, wb.w};
            #pragma unroll
            for (int j = 0; j < 8; ++j) {
                acc[0][j] += xv0 * wv[j];
                acc[1][j] += xv1 * wv[j];
            }
        }
        #pragma unroll
        for (int i = 0; i < 2; ++i) {
            int node = node0 + ng * 2 + i;
            if (node >= n_nodes) continue;
            if (m < 4) {
                uint4 o;
                o.x = pack2(acc[i][0], acc[i][1]);
                o.y = pack2(acc[i][2], acc[i][3]);
                o.z = pack2(acc[i][4], acc[i][5]);
                o.w = pack2(acc[i][6], acc[i][7]);
                *reinterpret_cast<uint4*>(
                    &y[((size_t)m * n_nodes + node) * 64 + cg * 8]) = o;
            } else {
                float4 oa = make_float4(acc[i][0] + bias[0], acc[i][1] + bias[1],
                                        acc[i][2] + bias[2], acc[i][3] + bias[3]);
                float4 ob = make_float4(acc[i][4] + bias[4], acc[i][5] + bias[5],
                                        acc[i][6] + bias[6], acc[i][7] + bias[7]);
                reinterpret_cast<float4*>(&out[(size_t)node * 64 + cg * 8])[0] = oa;
                reinterpret_cast<float4*>(&out[(size_t)node * 64 + cg * 8])[1] = ob;
            }
        }
    }
}

__global__ __launch_bounds__(256) void scatter_kernel(
    const int* __restrict__ ei, const int* __restrict__ et,
    const unsigned short* __restrict__ y, float* __restrict__ out,
    int n_edges, int n_nodes)
{
    long idx = (long)blockIdx.x * blockDim.x + threadIdx.x;
    if (idx >= (long)n_edges * 16) return;
    int e  = (int)(idx >> 4);
    int cq = (int)(idx & 15);
    int src  = ei[e];
    int dstn = ei[n_edges + e];
    int t    = et[e];
    ushort4 v = reinterpret_cast<const ushort4*>(y)[((long)t * n_nodes + src) * 16 + cq];
    float* o = out + (long)dstn * 64 + cq * 4;
    atomicAdd(o + 0, bf2f(v.x));
    atomicAdd(o + 1, bf2f(v.y));
    atomicAdd(o + 2, bf2f(v.z));
    atomicAdd(o + 3, bf2f(v.w));
}

__global__ __launch_bounds__(256) void gemm_root_kernel(
    const float* __restrict__ x, const float* __restrict__ root_w,
    const float* __restrict__ root_b, float* __restrict__ out, int n_nodes)
{
    __shared__ float xs[NT][65];
    __shared__ float ws[64][65];
    const int tid   = threadIdx.x;
    const int node0 = blockIdx.x * NT;
    #pragma unroll
    for (int i = 0; i < 4; ++i) {
        int v  = tid + i * 256;
        int r  = v >> 4;
        int cq = v & 15;
        float4 w4 = reinterpret_cast<const float4*>(root_w)[v];
        ws[r][cq * 4 + 0] = w4.x; ws[r][cq * 4 + 1] = w4.y;
        ws[r][cq * 4 + 2] = w4.z; ws[r][cq * 4 + 3] = w4.w;
        int node = node0 + r;
        float4 x4 = (node < n_nodes)
                        ? reinterpret_cast<const float4*>(x)[node * 16 + cq]
                        : make_float4(0.f, 0.f, 0.f, 0.f);
        xs[r][cq * 4 + 0] = x4.x; xs[r][cq * 4 + 1] = x4.y;
        xs[r][cq * 4 + 2] = x4.z; xs[r][cq * 4 + 3] = x4.w;
    }
    __syncthreads();
    const int tc = (tid & 15) * 4;
    const int tr = (tid >> 4) * 4;
    float acc[4][4];
    #pragma unroll
    for (int i = 0; i < 4; ++i)
        #pragma unroll
        for (int j = 0; j < 4; ++j) acc[i][j] = 0.f;
    #pragma unroll 4
    for (int k = 0; k < 64; ++k) {
        float xv[4], wv[4];
        #pragma unroll
        for (int i = 0; i < 4; ++i) xv[i] = xs[tr + i][k];
        #pragma unroll
        for (int j = 0; j < 4; ++j) wv[j] = ws[k][tc + j];
        #pragma unroll
        for (int i = 0; i < 4; ++i)
            #pragma unroll
            for (int j = 0; j < 4; ++j) acc[i][j] += xv[i] * wv[j];
    }
    #pragma unroll
    for (int i = 0; i < 4; ++i) {
        int node = node0 + tr + i;
        if (node < n_nodes) {
            float4 o = make_float4(acc[i][0] + root_b[tc + 0], acc[i][1] + root_b[tc + 1],
                                   acc[i][2] + root_b[tc + 2], acc[i][3] + root_b[tc + 3]);
            reinterpret_cast<float4*>(out)[node * 16 + (tc >> 2)] = o;
        }
    }
}

__global__ __launch_bounds__(256) void edge_direct_kernel(
    const float* __restrict__ x, const int* __restrict__ ei,
    const int* __restrict__ et, const float* __restrict__ weight,
    float* __restrict__ out, int n_edges)
{
    int gwave  = (int)((blockIdx.x * (long)blockDim.x + threadIdx.x) >> 6);
    int lane   = threadIdx.x & 63;
    int nwaves = (int)(((long)gridDim.x * blockDim.x) >> 6);
    for (int e = gwave; e < n_edges; e += nwaves) {
        int src  = ei[e];
        int dstn = ei[n_edges + e];
        int t    = et[e];
        float xv = x[src * 64 + lane];
        const float* __restrict__ W = weight + t * 4096;
        float acc = 0.f;
        #pragma unroll 8
        for (int k = 0; k < 64; ++k) {
            float xk = __shfl(xv, k);
            acc += xk * W[k * 64 + lane];
        }
        atomicAdd(&out[(long)dstn * 64 + lane], acc);
    }
}

extern "C" void kernel_launch(void* const* d_in, const int* in_sizes, int n_in,
                              void* d_out, int out_size, void* d_ws, size_t ws_size,
                              hipStream_t stream) {
    const float* x      = (const float*)d_in[0];
    const int*   ei     = (const int*)d_in[1];   // [2, E] int32
    const int*   et     = (const int*)d_in[2];   // [E]
    const float* weight = (const float*)d_in[3]; // [4, 64, 64]
    const float* root_w = (const float*)d_in[4]; // [64, 64]
    const float* root_b = (const float*)d_in[5]; // [64]
    float* out = (float*)d_out;

    const int n_nodes = in_sizes[0] / 64;
    const int n_edges = in_sizes[2];
    const int nb      = (n_nodes + 63) >> 6;

    int ssh = 1;
    while ((1 << ssh) < n_nodes) ++ssh;   // bits for src
    const int tsh = ssh + 6;              // 6 bits for local dst

    const size_t wt_bytes = 5 * 4096 * sizeof(unsigned short);   // 40 KB
    const size_t y_bytes  = (size_t)4 * n_nodes * 64 * sizeof(unsigned short);
    const size_t b_bytes  = wt_bytes + y_bytes +
        ((size_t)nb + 1 + (size_t)nb * CAPB + n_edges) * 4;

    if (nb <= NBMAX && tsh + 2 <= 32 && ws_size >= b_bytes) {
        unsigned short* wt      = (unsigned short*)d_ws;
        unsigned short* y       = (unsigned short*)((char*)d_ws + wt_bytes);
        int*            cursor  = (int*)((char*)d_ws + wt_bytes + y_bytes); // nb+1
        unsigned*       payload = (unsigned*)(cursor + nb + 1);             // nb*CAPB
        int*            spill   = (int*)(payload + (size_t)nb * CAPB);      // n_edges

        prep_w_kernel<<<80, 256, 0, stream>>>(weight, root_w, wt, cursor, nb);
        fused_fg_kernel<<<FILLB + nb, 256, 0, stream>>>(
            x, (const uint4*)wt, root_b, out, y, n_nodes,
            ei, et, cursor, spill, payload, n_edges, nb, ssh, tsh);
        gatherb3_kernel<<<nb, 1024, 0, stream>>>(
            cursor, payload, spill, ei, et, y, out,
            n_nodes, n_edges, nb, ssh, tsh);
    } else if (ws_size >= y_bytes) {
        unsigned short* y = (unsigned short*)d_ws;
        gemm_fused2_kernel<<<(n_nodes + 63) / 64, 256, 0, stream>>>(
            x, weight, root_w, root_b, out, y, n_nodes);
        long total  = (long)n_edges * 16;
        int  blocks = (int)((total + 255) / 256);
        scatter_kernel<<<blocks, 256, 0, stream>>>(ei, et, y, out, n_edges, n_nodes);
    } else {
        gemm_root_kernel<<<(n_nodes + NT - 1) / NT, 256, 0, stream>>>(
            x, root_w, root_b, out, n_nodes);
        edge_direct_kernel<<<4096, 256, 0, stream>>>(x, ei, et, weight, out, n_edges);
    }
}